// Round 1
// baseline (3374.216 us; speedup 1.0000x reference)
//
#include <hip/hip_runtime.h>

#define KDIR 100
#define TILE 4096
#define SBLK 256
#define ITEMS 16
#define NDIG 16
#define NPASS 8
#define MPT 32
#define MBLK 256

__device__ __forceinline__ unsigned encodeF(float f) {
  unsigned u = __float_as_uint(f);
  return u ^ ((u >> 31) ? 0xFFFFFFFFu : 0x80000000u);
}
__device__ __forceinline__ float decodeU(unsigned u) {
  return __uint_as_float(u ^ ((u >> 31) ? 0x80000000u : 0xFFFFFFFFu));
}

// tbl layout: [0..99]=cos, [128..227]=sin, [256..355]=c=(cos+sin)*invn, [384..483]=invn
__global__ void k_table(float* tbl, double* accum) {
  int k = threadIdx.x;
  const double PI = 3.14159265358979323846;
  if (k < KDIR) {
    double th = -PI * 0.5 + (double)k * (PI / (double)KDIR);
    float c = (float)cos(th), s = (float)sin(th);
    float invn = 1.0f / (c * c + s * s);
    tbl[k] = c; tbl[128 + k] = s; tbl[256 + k] = (c + s) * invn; tbl[384 + k] = invn;
  }
  if (k == 0) *accum = 0.0;
}

__global__ void k_buildS(const float* __restrict__ X, const float* __restrict__ Y,
                         int N, int M, unsigned* __restrict__ sx, unsigned* __restrict__ sy) {
  int i = blockIdx.x * blockDim.x + threadIdx.x;
  if (i < N) sx[i] = encodeF(0.5f * (X[2 * i] + X[2 * i + 1]));
  if (i < M) sy[i] = encodeF(0.5f * (Y[2 * i] + Y[2 * i + 1]));
}

__global__ void k_buildProj(const float* __restrict__ P, int n, int k0,
                            const float* __restrict__ tbl, unsigned* __restrict__ dst) {
  int i = blockIdx.x * blockDim.x + threadIdx.x;
  if (i >= n) return;
  int k = k0 + blockIdx.y;
  float x = P[2 * i], y = P[2 * i + 1];
  float pr = (x * tbl[k] + y * tbl[128 + k]) * tbl[384 + k];
  dst[(size_t)blockIdx.y * n + i] = encodeF(pr);
}

__global__ void k_hist(const unsigned* __restrict__ keys, int L, int T, int shift,
                       unsigned* __restrict__ counts) {
  __shared__ unsigned h[NDIG];
  int tid = threadIdx.x;
  if (tid < NDIG) h[tid] = 0;
  __syncthreads();
  int seg = blockIdx.y, tile = blockIdx.x;
  const unsigned* base = keys + (size_t)seg * L;
  int start = tile * TILE;
  int end = min(start + TILE, L);
  for (int i = start + tid; i < end; i += SBLK)
    atomicAdd(&h[(base[i] >> shift) & (NDIG - 1)], 1u);
  __syncthreads();
  if (tid < NDIG)
    counts[((size_t)seg * NDIG + tid) * T + tile] = h[tid];
}

// one block per segment: exclusive scan of counts[seg][digit][tile] (digit-major)
__global__ void k_scan(unsigned* __restrict__ counts, int T) {
  __shared__ unsigned tmp[SBLK];
  __shared__ unsigned carry;
  int tid = threadIdx.x;
  unsigned* c = counts + (size_t)blockIdx.x * NDIG * T;
  int total = NDIG * T;
  if (tid == 0) carry = 0;
  __syncthreads();
  for (int base = 0; base < total; base += SBLK) {
    int idx = base + tid;
    unsigned v = (idx < total) ? c[idx] : 0u;
    tmp[tid] = v;
    __syncthreads();
    for (int ofs = 1; ofs < SBLK; ofs <<= 1) {
      unsigned t = (tid >= ofs) ? tmp[tid - ofs] : 0u;
      __syncthreads();
      tmp[tid] += t;
      __syncthreads();
    }
    unsigned excl = tmp[tid] - v + carry;
    if (idx < total) c[idx] = excl;
    __syncthreads();
    if (tid == 0) carry += tmp[SBLK - 1];
    __syncthreads();
  }
}

__global__ __launch_bounds__(SBLK) void k_scatter(const unsigned* __restrict__ src,
                                                  unsigned* __restrict__ dst,
                                                  int L, int T, int shift,
                                                  const unsigned* __restrict__ counts) {
  __shared__ unsigned keys[TILE];                       // 16 KB
  __shared__ unsigned short cnt[NDIG][SBLK + 1];        // 8.2 KB
  __shared__ unsigned scanTmp[SBLK];
  __shared__ unsigned baseD[NDIG];
  int tid = threadIdx.x;
  int seg = blockIdx.y, tile = blockIdx.x;
  const unsigned* sbase = src + (size_t)seg * L;
  int start = tile * TILE;
  int nItems = min(TILE, L - start);
  for (int i = tid; i < TILE; i += SBLK)
    keys[i] = (i < nItems) ? sbase[start + i] : 0xFFFFFFFFu;
  for (int i = tid; i < NDIG * (SBLK + 1); i += SBLK)
    ((unsigned short*)cnt)[i] = 0;
  __syncthreads();
  int myBase = tid * ITEMS;
  int myValid = nItems - myBase;
  myValid = myValid < 0 ? 0 : (myValid > ITEMS ? ITEMS : myValid);
  unsigned long long digPack = 0ull, rlPack = 0ull;   // 4 bits per item each
#pragma unroll
  for (int i = 0; i < ITEMS; ++i) {
    if (i < myValid) {
      unsigned d = (keys[myBase + i] >> shift) & (NDIG - 1);
      unsigned prev = cnt[d][tid];
      cnt[d][tid] = (unsigned short)(prev + 1);
      digPack |= (unsigned long long)d << (4 * i);
      rlPack |= (unsigned long long)prev << (4 * i);
    }
  }
  __syncthreads();
  // exclusive scan over flattened f = d*256 + t; thread u owns f in [u*16, u*16+16)
  unsigned d0 = (unsigned)(tid >> 4);
  int t0 = (tid & 15) * ITEMS;
  unsigned run = 0;
#pragma unroll
  for (int i = 0; i < ITEMS; ++i) {
    unsigned v = cnt[d0][t0 + i];
    cnt[d0][t0 + i] = (unsigned short)run;
    run += v;
  }
  scanTmp[tid] = run;
  __syncthreads();
  for (int ofs = 1; ofs < SBLK; ofs <<= 1) {
    unsigned t = (tid >= ofs) ? scanTmp[tid - ofs] : 0u;
    __syncthreads();
    scanTmp[tid] += t;
    __syncthreads();
  }
  unsigned myOff = scanTmp[tid] - run;
#pragma unroll
  for (int i = 0; i < ITEMS; ++i)
    cnt[d0][t0 + i] = (unsigned short)(cnt[d0][t0 + i] + myOff);
  __syncthreads();
  if (tid < NDIG)
    baseD[tid] = counts[((size_t)seg * NDIG + tid) * T + tile] - (unsigned)cnt[tid][0];
  __syncthreads();
  unsigned* dbase = dst + (size_t)seg * L;
#pragma unroll
  for (int i = 0; i < ITEMS; ++i) {
    if (i < myValid) {
      unsigned d = (unsigned)((digPack >> (4 * i)) & 15ull);
      unsigned rl = (unsigned)((rlPack >> (4 * i)) & 15ull);
      dbase[baseD[d] + (unsigned)cnt[d][tid] + rl] = keys[myBase + i];
    }
  }
}

__device__ __forceinline__ float scaledAt(const unsigned* __restrict__ s, int len, int j,
                                          float c, int rev) {
  return c * decodeU(s[rev ? (len - 1 - j) : j]);
}

__device__ int mergeSplit(const unsigned* __restrict__ U, int n,
                          const unsigned* __restrict__ sV, int m,
                          float c, int rev, int o) {
  int lo = o - m; if (lo < 0) lo = 0;
  int hi = o < n ? o : n;
  while (lo < hi) {
    int mid = (lo + hi + 1) >> 1;
    if (decodeU(U[mid - 1]) <= scaledAt(sV, m, o - mid, c, rev)) lo = mid;
    else hi = mid - 1;
  }
  return lo;
}

__global__ void k_merge(const unsigned* __restrict__ pX, const unsigned* __restrict__ pY,
                        const unsigned* __restrict__ sx, const unsigned* __restrict__ sy,
                        int N, int M, int k0, const float* __restrict__ tbl,
                        double* __restrict__ accum) {
  const float FMAX = 3.402823466e38f;
  int kl = blockIdx.y;
  float c = tbl[256 + k0 + kl];
  int rev = c < 0.0f ? 1 : 0;
  int Stot = N + M;
  int o0 = (blockIdx.x * MBLK + threadIdx.x) * MPT;
  float acc = 0.0f;
  if (o0 < Stot) {
    int cntOut = min(MPT, Stot - o0);
    const unsigned* U1 = pX + (size_t)kl * N;   // A = merge(projX_k, c*sY)
    const unsigned* U2 = pY + (size_t)kl * M;   // B = merge(projY_k, c*sX)
    int a = mergeSplit(U1, N, sy, M, c, rev, o0);
    int b = o0 - a;
    int a2 = mergeSplit(U2, M, sx, N, c, rev, o0);
    int b2 = o0 - a2;
    float u1 = a < N ? decodeU(U1[a]) : FMAX;
    float v1 = b < M ? scaledAt(sy, M, b, c, rev) : FMAX;
    float u2 = a2 < M ? decodeU(U2[a2]) : FMAX;
    float v2 = b2 < N ? scaledAt(sx, N, b2, c, rev) : FMAX;
    for (int s = 0; s < cntOut; ++s) {
      float Av, Bv;
      if (u1 <= v1) { Av = u1; ++a; u1 = a < N ? decodeU(U1[a]) : FMAX; }
      else          { Av = v1; ++b; v1 = b < M ? scaledAt(sy, M, b, c, rev) : FMAX; }
      if (u2 <= v2) { Bv = u2; ++a2; u2 = a2 < M ? decodeU(U2[a2]) : FMAX; }
      else          { Bv = v2; ++b2; v2 = b2 < N ? scaledAt(sx, N, b2, c, rev) : FMAX; }
      acc += fabsf(Av - Bv);
    }
  }
  __shared__ float red[MBLK];
  red[threadIdx.x] = acc;
  __syncthreads();
  for (int ofs = MBLK / 2; ofs > 0; ofs >>= 1) {
    if (threadIdx.x < ofs) red[threadIdx.x] += red[threadIdx.x + ofs];
    __syncthreads();
  }
  if (threadIdx.x == 0) atomicAdd(accum, (double)red[0]);
}

__global__ void k_final(const double* __restrict__ accum, float* __restrict__ out) {
  out[0] = (float)(*accum / (double)KDIR);
}

extern "C" void kernel_launch(void* const* d_in, const int* in_sizes, int n_in,
                              void* d_out, int out_size, void* d_ws, size_t ws_size,
                              hipStream_t stream) {
  const float* X = (const float*)d_in[0];
  const float* Y = (const float*)d_in[1];
  int N = in_sizes[0] / 2;
  int M = in_sizes[1] / 2;

  char* ws = (char*)d_ws;
  size_t off = 0;
  auto alloc = [&](size_t b) -> void* {
    void* p = ws + off;
    off += (b + 255) & ~(size_t)255;
    return p;
  };
  float* tbl = (float*)alloc(512 * sizeof(float));
  double* accum = (double*)alloc(256);
  unsigned* sPing = (unsigned*)alloc((size_t)(N + M) * 4);
  unsigned* sPong = (unsigned*)alloc((size_t)(N + M) * 4);
  int Tn = (N + TILE - 1) / TILE;
  int Tm = (M + TILE - 1) / TILE;
  int Tmax = Tn > Tm ? Tn : Tm;
  unsigned* counts = (unsigned*)alloc((size_t)(2 * KDIR) * NDIG * Tmax * 4);

  // chunk as many directions as ws allows (per dir: ping+pong for projX+projY)
  size_t perDir = (size_t)(N + M) * 8;
  size_t remain = ws_size > off ? ws_size - off : 0;
  int Kc = (int)(remain / perDir);
  if (Kc > KDIR) Kc = KDIR;
  if (Kc < 1) Kc = 1;
  unsigned* cPing = (unsigned*)alloc((size_t)Kc * (size_t)(N + M) * 4);
  unsigned* cPong = (unsigned*)alloc((size_t)Kc * (size_t)(N + M) * 4);

  k_table<<<1, 128, 0, stream>>>(tbl, accum);
  int mx = N > M ? N : M;
  k_buildS<<<(mx + 255) / 256, 256, 0, stream>>>(X, Y, N, M, sPing, sPing + N);

  auto sortJob = [&](unsigned* ping, unsigned* pong, int segs, int L) {
    int T = (L + TILE - 1) / TILE;
    unsigned* s = ping;
    unsigned* d = pong;
    for (int p = 0; p < NPASS; ++p) {
      int shift = 4 * p;
      k_hist<<<dim3(T, segs), SBLK, 0, stream>>>(s, L, T, shift, counts);
      k_scan<<<segs, SBLK, 0, stream>>>(counts, T);
      k_scatter<<<dim3(T, segs), SBLK, 0, stream>>>(s, d, L, T, shift, counts);
      unsigned* t = s; s = d; d = t;
    }
    // NPASS even -> sorted result back in `ping`
  };

  if (N == M) sortJob(sPing, sPong, 2, N);
  else { sortJob(sPing, sPong, 1, N); sortJob(sPing + N, sPong, 1, M); }

  for (int k0 = 0; k0 < KDIR; k0 += Kc) {
    int kc = (KDIR - k0 < Kc) ? (KDIR - k0) : Kc;
    unsigned* pX = cPing;
    unsigned* pY = cPing + (size_t)kc * N;
    k_buildProj<<<dim3((N + 255) / 256, kc), 256, 0, stream>>>(X, N, k0, tbl, pX);
    k_buildProj<<<dim3((M + 255) / 256, kc), 256, 0, stream>>>(Y, M, k0, tbl, pY);
    if (N == M) sortJob(cPing, cPong, 2 * kc, N);
    else { sortJob(pX, cPong, kc, N); sortJob(pY, cPong, kc, M); }
    int Stot = N + M;
    int mBlocks = (Stot + MBLK * MPT - 1) / (MBLK * MPT);
    k_merge<<<dim3(mBlocks, kc), MBLK, 0, stream>>>(pX, pY, sPing, sPing + N, N, M, k0, tbl, accum);
  }
  k_final<<<1, 1, 0, stream>>>(accum, (float*)d_out);
}

// Round 2
// 2761.621 us; speedup vs baseline: 1.2218x; 1.2218x over previous
//
#include <hip/hip_runtime.h>

#define KDIR 100
#define TILE 4096
#define SBLK 256
#define ITEMS 16
#define NDIG 16
#define NPASS 8
#define MBLK 256
#define MOUT 4096
#define MPT2 (MOUT / MBLK)

__device__ __forceinline__ unsigned encodeF(float f) {
  unsigned u = __float_as_uint(f);
  return u ^ ((u >> 31) ? 0xFFFFFFFFu : 0x80000000u);
}
__device__ __forceinline__ float decodeU(unsigned u) {
  return __uint_as_float(u ^ ((u >> 31) ? 0x80000000u : 0xFFFFFFFFu));
}

// tbl layout: [0..99]=cos, [128..227]=sin, [256..355]=c=(cos+sin)*invn, [384..483]=invn
__global__ void k_table(float* tbl, double* accum) {
  int k = threadIdx.x;
  const double PI = 3.14159265358979323846;
  if (k < KDIR) {
    double th = -PI * 0.5 + (double)k * (PI / (double)KDIR);
    float c = (float)cos(th), s = (float)sin(th);
    float invn = 1.0f / (c * c + s * s);
    tbl[k] = c; tbl[128 + k] = s; tbl[256 + k] = (c + s) * invn; tbl[384 + k] = invn;
  }
  if (k == 0) *accum = 0.0;
}

__global__ void k_buildS(const float* __restrict__ X, const float* __restrict__ Y,
                         int N, int M, unsigned* __restrict__ sx, unsigned* __restrict__ sy) {
  int i = blockIdx.x * blockDim.x + threadIdx.x;
  if (i < N) sx[i] = encodeF(0.5f * (X[2 * i] + X[2 * i + 1]));
  if (i < M) sy[i] = encodeF(0.5f * (Y[2 * i] + Y[2 * i + 1]));
}

__global__ void k_buildProj(const float* __restrict__ P, int n, int k0,
                            const float* __restrict__ tbl, unsigned* __restrict__ dst) {
  int i = blockIdx.x * blockDim.x + threadIdx.x;
  if (i >= n) return;
  int k = k0 + blockIdx.y;
  float x = P[2 * i], y = P[2 * i + 1];
  float pr = (x * tbl[k] + y * tbl[128 + k]) * tbl[384 + k];
  dst[(size_t)blockIdx.y * n + i] = encodeF(pr);
}

__global__ void k_hist(const unsigned* __restrict__ keys, int L, int T, int shift,
                       unsigned* __restrict__ counts) {
  __shared__ unsigned h[NDIG];
  int tid = threadIdx.x;
  if (tid < NDIG) h[tid] = 0;
  __syncthreads();
  int seg = blockIdx.y, tile = blockIdx.x;
  const unsigned* base = keys + (size_t)seg * L;
  int start = tile * TILE;
  int end = min(start + TILE, L);
  for (int i = start + tid; i < end; i += SBLK)
    atomicAdd(&h[(base[i] >> shift) & (NDIG - 1)], 1u);
  __syncthreads();
  if (tid < NDIG)
    counts[((size_t)seg * NDIG + tid) * T + tile] = h[tid];
}

// one block per segment: exclusive scan of counts[seg][digit][tile] (digit-major)
__global__ void k_scan(unsigned* __restrict__ counts, int T) {
  __shared__ unsigned tmp[SBLK];
  __shared__ unsigned carry;
  int tid = threadIdx.x;
  unsigned* c = counts + (size_t)blockIdx.x * NDIG * T;
  int total = NDIG * T;
  if (tid == 0) carry = 0;
  __syncthreads();
  for (int base = 0; base < total; base += SBLK) {
    int idx = base + tid;
    unsigned v = (idx < total) ? c[idx] : 0u;
    tmp[tid] = v;
    __syncthreads();
    for (int ofs = 1; ofs < SBLK; ofs <<= 1) {
      unsigned t = (tid >= ofs) ? tmp[tid - ofs] : 0u;
      __syncthreads();
      tmp[tid] += t;
      __syncthreads();
    }
    unsigned excl = tmp[tid] - v + carry;
    if (idx < total) c[idx] = excl;
    __syncthreads();
    if (tid == 0) carry += tmp[SBLK - 1];
    __syncthreads();
  }
}

__global__ __launch_bounds__(SBLK) void k_scatter(const unsigned* __restrict__ src,
                                                  unsigned* __restrict__ dst,
                                                  int L, int T, int shift,
                                                  const unsigned* __restrict__ counts) {
  __shared__ unsigned keys[TILE];                       // 16 KB
  __shared__ unsigned short cnt[NDIG][SBLK + 1];        // 8.2 KB
  __shared__ unsigned scanTmp[SBLK];
  __shared__ unsigned baseD[NDIG];
  int tid = threadIdx.x;
  int seg = blockIdx.y, tile = blockIdx.x;
  const unsigned* sbase = src + (size_t)seg * L;
  int start = tile * TILE;
  int nItems = min(TILE, L - start);
  for (int i = tid; i < TILE; i += SBLK)
    keys[i] = (i < nItems) ? sbase[start + i] : 0xFFFFFFFFu;
  for (int i = tid; i < NDIG * (SBLK + 1); i += SBLK)
    ((unsigned short*)cnt)[i] = 0;
  __syncthreads();
  int myBase = tid * ITEMS;
  int myValid = nItems - myBase;
  myValid = myValid < 0 ? 0 : (myValid > ITEMS ? ITEMS : myValid);
  unsigned long long digPack = 0ull, rlPack = 0ull;   // 4 bits per item each
#pragma unroll
  for (int i = 0; i < ITEMS; ++i) {
    if (i < myValid) {
      unsigned d = (keys[myBase + i] >> shift) & (NDIG - 1);
      unsigned prev = cnt[d][tid];
      cnt[d][tid] = (unsigned short)(prev + 1);
      digPack |= (unsigned long long)d << (4 * i);
      rlPack |= (unsigned long long)prev << (4 * i);
    }
  }
  __syncthreads();
  // exclusive scan over flattened f = d*256 + t; thread u owns f in [u*16, u*16+16)
  unsigned d0 = (unsigned)(tid >> 4);
  int t0 = (tid & 15) * ITEMS;
  unsigned run = 0;
#pragma unroll
  for (int i = 0; i < ITEMS; ++i) {
    unsigned v = cnt[d0][t0 + i];
    cnt[d0][t0 + i] = (unsigned short)run;
    run += v;
  }
  scanTmp[tid] = run;
  __syncthreads();
  for (int ofs = 1; ofs < SBLK; ofs <<= 1) {
    unsigned t = (tid >= ofs) ? scanTmp[tid - ofs] : 0u;
    __syncthreads();
    scanTmp[tid] += t;
    __syncthreads();
  }
  unsigned myOff = scanTmp[tid] - run;
#pragma unroll
  for (int i = 0; i < ITEMS; ++i)
    cnt[d0][t0 + i] = (unsigned short)(cnt[d0][t0 + i] + myOff);
  __syncthreads();
  if (tid < NDIG)
    baseD[tid] = counts[((size_t)seg * NDIG + tid) * T + tile] - (unsigned)cnt[tid][0];
  __syncthreads();
  unsigned* dbase = dst + (size_t)seg * L;
#pragma unroll
  for (int i = 0; i < ITEMS; ++i) {
    if (i < myValid) {
      unsigned d = (unsigned)((digPack >> (4 * i)) & 15ull);
      unsigned rl = (unsigned)((rlPack >> (4 * i)) & 15ull);
      dbase[baseD[d] + (unsigned)cnt[d][tid] + rl] = keys[myBase + i];
    }
  }
}

__device__ __forceinline__ float scaledAt(const unsigned* __restrict__ s, int len, int j,
                                          float c, int rev) {
  return c * decodeU(s[rev ? (len - 1 - j) : j]);
}

__device__ int mergeSplit(const unsigned* __restrict__ U, int n,
                          const unsigned* __restrict__ sV, int m,
                          float c, int rev, int o) {
  int lo = o - m; if (lo < 0) lo = 0;
  int hi = o < n ? o : n;
  while (lo < hi) {
    int mid = (lo + hi + 1) >> 1;
    if (decodeU(U[mid - 1]) <= scaledAt(sV, m, o - mid, c, rev)) lo = mid;
    else hi = mid - 1;
  }
  return lo;
}

// split within LDS float arrays, same comparator (a-side wins ties)
__device__ __forceinline__ int ldsSplit(const float* __restrict__ a, int n,
                                        const float* __restrict__ b, int m, int o) {
  int lo = o - m; if (lo < 0) lo = 0;
  int hi = o < n ? o : n;
  while (lo < hi) {
    int mid = (lo + hi + 1) >> 1;
    if (a[mid - 1] <= b[o - mid]) lo = mid;
    else hi = mid - 1;
  }
  return lo;
}

__global__ __launch_bounds__(MBLK) void k_merge(const unsigned* __restrict__ pX,
                                                const unsigned* __restrict__ pY,
                                                const unsigned* __restrict__ sx,
                                                const unsigned* __restrict__ sy,
                                                int N, int M, int k0,
                                                const float* __restrict__ tbl,
                                                double* __restrict__ accum) {
  const float FMAX = 3.402823466e38f;
  __shared__ float sA[MOUT];   // A-merge inputs: [0..aCnt) from pX_k, [aCnt..outCnt) = c*sy
  __shared__ float sB[MOUT];   // B-merge inputs: [0..a2Cnt) from pY_k, rest = c*sx
  __shared__ int splits[4];
  __shared__ float red[MBLK];
  int kl = blockIdx.y;
  float c = tbl[256 + k0 + kl];
  int rev = c < 0.0f ? 1 : 0;
  int Stot = N + M;
  int o0 = blockIdx.x * MOUT;
  int outCnt = min(MOUT, Stot - o0);
  const unsigned* U1 = pX + (size_t)kl * N;
  const unsigned* U2 = pY + (size_t)kl * M;
  int tid = threadIdx.x;
  if (tid == 0)        splits[0] = mergeSplit(U1, N, sy, M, c, rev, o0);
  else if (tid == 64)  splits[1] = mergeSplit(U1, N, sy, M, c, rev, o0 + outCnt);
  else if (tid == 128) splits[2] = mergeSplit(U2, M, sx, N, c, rev, o0);
  else if (tid == 192) splits[3] = mergeSplit(U2, M, sx, N, c, rev, o0 + outCnt);
  __syncthreads();
  int aLo = splits[0], aCnt = splits[1] - aLo;
  int bLo = o0 - aLo, bCnt = outCnt - aCnt;
  int a2Lo = splits[2], a2Cnt = splits[3] - a2Lo;
  int b2Lo = o0 - a2Lo, b2Cnt = outCnt - a2Cnt;
  for (int i = tid; i < aCnt; i += MBLK) sA[i] = decodeU(U1[aLo + i]);
  for (int i = tid; i < bCnt; i += MBLK) {
    int j = bLo + i;
    sA[aCnt + i] = c * decodeU(sy[rev ? (M - 1 - j) : j]);
  }
  for (int i = tid; i < a2Cnt; i += MBLK) sB[i] = decodeU(U2[a2Lo + i]);
  for (int i = tid; i < b2Cnt; i += MBLK) {
    int j = b2Lo + i;
    sB[a2Cnt + i] = c * decodeU(sx[rev ? (N - 1 - j) : j]);
  }
  __syncthreads();
  float acc = 0.0f;
  int lo0 = tid * MPT2;
  if (lo0 < outCnt) {
    int cnt = min(MPT2, outCnt - lo0);
    int la = ldsSplit(sA, aCnt, sA + aCnt, bCnt, lo0);
    int lb = lo0 - la;
    int la2 = ldsSplit(sB, a2Cnt, sB + a2Cnt, b2Cnt, lo0);
    int lb2 = lo0 - la2;
    float u1 = la < aCnt ? sA[la] : FMAX;
    float v1 = lb < bCnt ? sA[aCnt + lb] : FMAX;
    float u2 = la2 < a2Cnt ? sB[la2] : FMAX;
    float v2 = lb2 < b2Cnt ? sB[a2Cnt + lb2] : FMAX;
    for (int s = 0; s < cnt; ++s) {
      float Av, Bv;
      if (u1 <= v1) { Av = u1; ++la; u1 = la < aCnt ? sA[la] : FMAX; }
      else          { Av = v1; ++lb; v1 = lb < bCnt ? sA[aCnt + lb] : FMAX; }
      if (u2 <= v2) { Bv = u2; ++la2; u2 = la2 < a2Cnt ? sB[la2] : FMAX; }
      else          { Bv = v2; ++lb2; v2 = lb2 < b2Cnt ? sB[a2Cnt + lb2] : FMAX; }
      acc += fabsf(Av - Bv);
    }
  }
  red[tid] = acc;
  __syncthreads();
  for (int ofs = MBLK / 2; ofs > 0; ofs >>= 1) {
    if (tid < ofs) red[tid] += red[tid + ofs];
    __syncthreads();
  }
  if (tid == 0) atomicAdd(accum, (double)red[0]);
}

__global__ void k_final(const double* __restrict__ accum, float* __restrict__ out) {
  out[0] = (float)(*accum / (double)KDIR);
}

extern "C" void kernel_launch(void* const* d_in, const int* in_sizes, int n_in,
                              void* d_out, int out_size, void* d_ws, size_t ws_size,
                              hipStream_t stream) {
  const float* X = (const float*)d_in[0];
  const float* Y = (const float*)d_in[1];
  int N = in_sizes[0] / 2;
  int M = in_sizes[1] / 2;

  char* ws = (char*)d_ws;
  size_t off = 0;
  auto alloc = [&](size_t b) -> void* {
    void* p = ws + off;
    off += (b + 255) & ~(size_t)255;
    return p;
  };
  float* tbl = (float*)alloc(512 * sizeof(float));
  double* accum = (double*)alloc(256);
  unsigned* sPing = (unsigned*)alloc((size_t)(N + M) * 4);
  unsigned* sPong = (unsigned*)alloc((size_t)(N + M) * 4);
  int Tn = (N + TILE - 1) / TILE;
  int Tm = (M + TILE - 1) / TILE;
  int Tmax = Tn > Tm ? Tn : Tm;
  unsigned* counts = (unsigned*)alloc((size_t)(2 * KDIR) * NDIG * Tmax * 4);

  // chunk as many directions as ws allows (per dir: ping+pong for projX+projY)
  size_t perDir = (size_t)(N + M) * 8;
  size_t remain = ws_size > off ? ws_size - off : 0;
  int Kc = (int)(remain / perDir);
  if (Kc > KDIR) Kc = KDIR;
  if (Kc < 1) Kc = 1;
  unsigned* cPing = (unsigned*)alloc((size_t)Kc * (size_t)(N + M) * 4);
  unsigned* cPong = (unsigned*)alloc((size_t)Kc * (size_t)(N + M) * 4);

  k_table<<<1, 128, 0, stream>>>(tbl, accum);
  int mx = N > M ? N : M;
  k_buildS<<<(mx + 255) / 256, 256, 0, stream>>>(X, Y, N, M, sPing, sPing + N);

  auto sortJob = [&](unsigned* ping, unsigned* pong, int segs, int L) {
    int T = (L + TILE - 1) / TILE;
    unsigned* s = ping;
    unsigned* d = pong;
    for (int p = 0; p < NPASS; ++p) {
      int shift = 4 * p;
      k_hist<<<dim3(T, segs), SBLK, 0, stream>>>(s, L, T, shift, counts);
      k_scan<<<segs, SBLK, 0, stream>>>(counts, T);
      k_scatter<<<dim3(T, segs), SBLK, 0, stream>>>(s, d, L, T, shift, counts);
      unsigned* t = s; s = d; d = t;
    }
    // NPASS even -> sorted result back in `ping`
  };

  if (N == M) sortJob(sPing, sPong, 2, N);
  else { sortJob(sPing, sPong, 1, N); sortJob(sPing + N, sPong, 1, M); }

  for (int k0 = 0; k0 < KDIR; k0 += Kc) {
    int kc = (KDIR - k0 < Kc) ? (KDIR - k0) : Kc;
    unsigned* pX = cPing;
    unsigned* pY = cPing + (size_t)kc * N;
    k_buildProj<<<dim3((N + 255) / 256, kc), 256, 0, stream>>>(X, N, k0, tbl, pX);
    k_buildProj<<<dim3((M + 255) / 256, kc), 256, 0, stream>>>(Y, M, k0, tbl, pY);
    if (N == M) sortJob(cPing, cPong, 2 * kc, N);
    else { sortJob(pX, cPong, kc, N); sortJob(pY, cPong, kc, M); }
    int Stot = N + M;
    int mBlocks = (Stot + MOUT - 1) / MOUT;
    k_merge<<<dim3(mBlocks, kc), MBLK, 0, stream>>>(pX, pY, sPing, sPing + N, N, M, k0, tbl, accum);
  }
  k_final<<<1, 1, 0, stream>>>(accum, (float*)d_out);
}

// Round 4
// 2046.104 us; speedup vs baseline: 1.6491x; 1.3497x over previous
//
#include <hip/hip_runtime.h>

#define KDIR 100
#define TILE 4096
#define NPASS 3
#define MBLK 256
#define MOUT 4096
#define MPT2 (MOUT / MBLK)

__device__ __forceinline__ unsigned encodeF(float f) {
  unsigned u = __float_as_uint(f);
  return u ^ ((u >> 31) ? 0xFFFFFFFFu : 0x80000000u);
}
__device__ __forceinline__ float decodeU(unsigned u) {
  return __uint_as_float(u ^ ((u >> 31) ? 0x80000000u : 0xFFFFFFFFu));
}

// tbl layout: [0..99]=cos, [128..227]=sin, [256..355]=c=(cos+sin)*invn, [384..483]=invn
__global__ void k_table(float* tbl, double* accum) {
  int k = threadIdx.x;
  const double PI = 3.14159265358979323846;
  if (k < KDIR) {
    double th = -PI * 0.5 + (double)k * (PI / (double)KDIR);
    float c = (float)cos(th), s = (float)sin(th);
    float invn = 1.0f / (c * c + s * s);
    tbl[k] = c; tbl[128 + k] = s; tbl[256 + k] = (c + s) * invn; tbl[384 + k] = invn;
  }
  if (k == 0) *accum = 0.0;
}

__global__ void k_buildS(const float* __restrict__ X, const float* __restrict__ Y,
                         int N, int M, unsigned* __restrict__ sx, unsigned* __restrict__ sy) {
  int i = blockIdx.x * blockDim.x + threadIdx.x;
  if (i < N) sx[i] = encodeF(0.5f * (X[2 * i] + X[2 * i + 1]));
  if (i < M) sy[i] = encodeF(0.5f * (Y[2 * i] + Y[2 * i + 1]));
}

__global__ void k_buildProj(const float* __restrict__ P, int n, int k0,
                            const float* __restrict__ tbl, unsigned* __restrict__ dst) {
  int i = blockIdx.x * blockDim.x + threadIdx.x;
  if (i >= n) return;
  int k = k0 + blockIdx.y;
  float x = P[2 * i], y = P[2 * i + 1];
  float pr = (x * tbl[k] + y * tbl[128 + k]) * tbl[384 + k];
  dst[(size_t)blockIdx.y * n + i] = encodeF(pr);
}

// Per-pass 8-bit histogram on the CURRENT pass input (per-tile counts are
// input-order dependent — cannot be fused across passes).
// counts[(seg*256 + d)*T + tile]
__global__ __launch_bounds__(256) void k_hist8(const unsigned* __restrict__ keys,
                                               int L, int T, int shift,
                                               unsigned* __restrict__ counts) {
  __shared__ unsigned h[256];
  int tid = threadIdx.x;
  int lane = tid & 63;
  h[tid] = 0;
  __syncthreads();
  int seg = blockIdx.y, tile = blockIdx.x;
  const unsigned* base = keys + (size_t)seg * L;
  int start = tile * TILE;
  int nItems = min(TILE, L - start);
  for (int i = tid; i < nItems; i += 256) {
    unsigned d = (base[start + i] >> shift) & 255u;
    unsigned long long act = __ballot(1);
    unsigned long long mask = act;
#pragma unroll
    for (int b = 0; b < 8; ++b) {
      unsigned long long bal = __ballot((d >> b) & 1);
      mask &= ((d >> b) & 1) ? bal : ~bal;
    }
    if ((mask & ((1ull << lane) - 1ull)) == 0ull)
      atomicAdd(&h[d], (unsigned)__popcll(mask));
  }
  __syncthreads();
  counts[((size_t)seg * 256 + tid) * T + tile] = h[tid];
}

// barrier-free per-segment exclusive scan of [256*T] counters, one wave per segment
__global__ void k_scan64(unsigned* __restrict__ counts, int total) {
  unsigned* c = counts + (size_t)blockIdx.x * total;
  int lane = threadIdx.x;
  unsigned carry = 0;
  for (int base = 0; base < total; base += 64) {
    unsigned v = c[base + lane];
    unsigned x = v;
#pragma unroll
    for (int ofs = 1; ofs < 64; ofs <<= 1) {
      unsigned t = __shfl_up(x, ofs, 64);
      if (lane >= ofs) x += t;
    }
    c[base + lane] = x - v + carry;
    carry += __shfl(x, 63, 64);
  }
}

// 8-bit-digit scatter with ballot ranking. Stable in input order (w, i, lane).
__global__ __launch_bounds__(256) void k_scatter8(const unsigned* __restrict__ src,
                                                  unsigned* __restrict__ dst,
                                                  int L, int T, int shift,
                                                  const unsigned* __restrict__ counts) {
  __shared__ unsigned keys[TILE];            // 16 KB
  __shared__ unsigned runW[4][256];          // 4 KB: per-wave digit counters -> offsets
  __shared__ unsigned short rnk[TILE];       // 8 KB
  int tid = threadIdx.x;
  int lane = tid & 63, w = tid >> 6;
  int seg = blockIdx.y, tile = blockIdx.x;
  const unsigned* sbase = src + (size_t)seg * L;
  int start = tile * TILE;
  int nItems = min(TILE, L - start);
  for (int i = tid; i < TILE; i += 256)
    keys[i] = (i < nItems) ? sbase[start + i] : 0xFFFFFFFFu;
  for (int i = tid; i < 4 * 256; i += 256) ((unsigned*)runW)[i] = 0;
  __syncthreads();
  // per-wave ranking, wave-synchronous (no block sync inside the loop)
#pragma unroll
  for (int i = 0; i < TILE / 256; ++i) {
    int j = w * (TILE / 4) + i * 64 + lane;
    bool valid = j < nItems;
    unsigned long long act = __ballot(valid);
    if (valid) {
      unsigned k = keys[j];
      unsigned d = (k >> shift) & 255u;
      unsigned long long mask = act;
#pragma unroll
      for (int b = 0; b < 8; ++b) {
        unsigned long long bal = __ballot((d >> b) & 1);
        mask &= ((d >> b) & 1) ? bal : ~bal;
      }
      unsigned r = (unsigned)__popcll(mask & ((1ull << lane) - 1ull));
      unsigned prev = runW[w][d];            // broadcast read within digit group
      rnk[j] = (unsigned short)(prev + r);
      if (r == 0) runW[w][d] = prev + (unsigned)__popcll(mask);  // leader updates
    }
  }
  __syncthreads();
  // fold global digit base + cross-wave prefix into runW
  {
    unsigned s = counts[((size_t)seg * 256 + tid) * T + tile];
#pragma unroll
    for (int ww = 0; ww < 4; ++ww) {
      unsigned t = runW[ww][tid];
      runW[ww][tid] = s;
      s += t;
    }
  }
  __syncthreads();
  unsigned* dbase = dst + (size_t)seg * L;
  for (int jj = tid; jj < nItems; jj += 256) {
    unsigned k = keys[jj];
    unsigned d = (k >> shift) & 255u;
    int ww = jj / (TILE / 4);
    dbase[runW[ww][d] + (unsigned)rnk[jj]] = k;
  }
}

__device__ __forceinline__ float scaledAt(const unsigned* __restrict__ s, int len, int j,
                                          float c, int rev) {
  return c * decodeU(s[rev ? (len - 1 - j) : j]);
}

__device__ int mergeSplit(const unsigned* __restrict__ U, int n,
                          const unsigned* __restrict__ sV, int m,
                          float c, int rev, int o) {
  int lo = o - m; if (lo < 0) lo = 0;
  int hi = o < n ? o : n;
  while (lo < hi) {
    int mid = (lo + hi + 1) >> 1;
    if (decodeU(U[mid - 1]) <= scaledAt(sV, m, o - mid, c, rev)) lo = mid;
    else hi = mid - 1;
  }
  return lo;
}

__device__ __forceinline__ int ldsSplit(const float* __restrict__ a, int n,
                                        const float* __restrict__ b, int m, int o) {
  int lo = o - m; if (lo < 0) lo = 0;
  int hi = o < n ? o : n;
  while (lo < hi) {
    int mid = (lo + hi + 1) >> 1;
    if (a[mid - 1] <= b[o - mid]) lo = mid;
    else hi = mid - 1;
  }
  return lo;
}

__global__ __launch_bounds__(MBLK) void k_merge(const unsigned* __restrict__ pX,
                                                const unsigned* __restrict__ pY,
                                                const unsigned* __restrict__ sx,
                                                const unsigned* __restrict__ sy,
                                                int N, int M, int k0,
                                                const float* __restrict__ tbl,
                                                double* __restrict__ accum) {
  const float FMAX = 3.402823466e38f;
  __shared__ float sA[MOUT];
  __shared__ float sB[MOUT];
  __shared__ int splits[4];
  __shared__ float red[MBLK];
  int kl = blockIdx.y;
  float c = tbl[256 + k0 + kl];
  int rev = c < 0.0f ? 1 : 0;
  int Stot = N + M;
  int o0 = blockIdx.x * MOUT;
  int outCnt = min(MOUT, Stot - o0);
  const unsigned* U1 = pX + (size_t)kl * N;
  const unsigned* U2 = pY + (size_t)kl * M;
  int tid = threadIdx.x;
  if (tid == 0)        splits[0] = mergeSplit(U1, N, sy, M, c, rev, o0);
  else if (tid == 64)  splits[1] = mergeSplit(U1, N, sy, M, c, rev, o0 + outCnt);
  else if (tid == 128) splits[2] = mergeSplit(U2, M, sx, N, c, rev, o0);
  else if (tid == 192) splits[3] = mergeSplit(U2, M, sx, N, c, rev, o0 + outCnt);
  __syncthreads();
  int aLo = splits[0], aCnt = splits[1] - aLo;
  int bLo = o0 - aLo, bCnt = outCnt - aCnt;
  int a2Lo = splits[2], a2Cnt = splits[3] - a2Lo;
  int b2Lo = o0 - a2Lo, b2Cnt = outCnt - a2Cnt;
  for (int i = tid; i < aCnt; i += MBLK) sA[i] = decodeU(U1[aLo + i]);
  for (int i = tid; i < bCnt; i += MBLK) {
    int j = bLo + i;
    sA[aCnt + i] = c * decodeU(sy[rev ? (M - 1 - j) : j]);
  }
  for (int i = tid; i < a2Cnt; i += MBLK) sB[i] = decodeU(U2[a2Lo + i]);
  for (int i = tid; i < b2Cnt; i += MBLK) {
    int j = b2Lo + i;
    sB[a2Cnt + i] = c * decodeU(sx[rev ? (N - 1 - j) : j]);
  }
  __syncthreads();
  float acc = 0.0f;
  int lo0 = tid * MPT2;
  if (lo0 < outCnt) {
    int cnt = min(MPT2, outCnt - lo0);
    int la = ldsSplit(sA, aCnt, sA + aCnt, bCnt, lo0);
    int lb = lo0 - la;
    int la2 = ldsSplit(sB, a2Cnt, sB + a2Cnt, b2Cnt, lo0);
    int lb2 = lo0 - la2;
    float u1 = la < aCnt ? sA[la] : FMAX;
    float v1 = lb < bCnt ? sA[aCnt + lb] : FMAX;
    float u2 = la2 < a2Cnt ? sB[la2] : FMAX;
    float v2 = lb2 < b2Cnt ? sB[a2Cnt + lb2] : FMAX;
    for (int s = 0; s < cnt; ++s) {
      float Av, Bv;
      if (u1 <= v1) { Av = u1; ++la; u1 = la < aCnt ? sA[la] : FMAX; }
      else          { Av = v1; ++lb; v1 = lb < bCnt ? sA[aCnt + lb] : FMAX; }
      if (u2 <= v2) { Bv = u2; ++la2; u2 = la2 < a2Cnt ? sB[la2] : FMAX; }
      else          { Bv = v2; ++lb2; v2 = lb2 < b2Cnt ? sB[a2Cnt + lb2] : FMAX; }
      acc += fabsf(Av - Bv);
    }
  }
  red[tid] = acc;
  __syncthreads();
  for (int ofs = MBLK / 2; ofs > 0; ofs >>= 1) {
    if (tid < ofs) red[tid] += red[tid + ofs];
    __syncthreads();
  }
  if (tid == 0) atomicAdd(accum, (double)red[0]);
}

__global__ void k_final(const double* __restrict__ accum, float* __restrict__ out) {
  out[0] = (float)(*accum / (double)KDIR);
}

extern "C" void kernel_launch(void* const* d_in, const int* in_sizes, int n_in,
                              void* d_out, int out_size, void* d_ws, size_t ws_size,
                              hipStream_t stream) {
  const float* X = (const float*)d_in[0];
  const float* Y = (const float*)d_in[1];
  int N = in_sizes[0] / 2;
  int M = in_sizes[1] / 2;

  char* ws = (char*)d_ws;
  size_t off = 0;
  auto alloc = [&](size_t b) -> void* {
    void* p = ws + off;
    off += (b + 255) & ~(size_t)255;
    return p;
  };
  float* tbl = (float*)alloc(512 * sizeof(float));
  double* accum = (double*)alloc(256);
  unsigned* sPing = (unsigned*)alloc((size_t)(N + M) * 4);
  unsigned* sPong = (unsigned*)alloc((size_t)(N + M) * 4);

  int Tn = (N + TILE - 1) / TILE;
  int Tm = (M + TILE - 1) / TILE;
  int Tmax = Tn > Tm ? Tn : Tm;

  // per direction: ping+pong keys (2 segs) + counts (2 segs x 256 x Tmax)
  size_t perDir = (size_t)(N + M) * 8 + (size_t)2 * 256 * Tmax * 4;
  size_t remain = ws_size > off ? ws_size - off : 0;
  int Kc = (int)(remain / perDir);
  if (Kc > KDIR) Kc = KDIR;
  if (Kc < 1) Kc = 1;
  int maxSegs = 2 * Kc;  // >= 2 (diag sort) since Kc >= 1
  unsigned* counts8 = (unsigned*)alloc((size_t)maxSegs * 256 * Tmax * 4);
  unsigned* cPing = (unsigned*)alloc((size_t)Kc * (size_t)(N + M) * 4);
  unsigned* cPong = (unsigned*)alloc((size_t)Kc * (size_t)(N + M) * 4);

  k_table<<<1, 128, 0, stream>>>(tbl, accum);
  int mx = N > M ? N : M;
  // stage diag keys in PONG so 3 (odd) passes end in PING
  k_buildS<<<(mx + 255) / 256, 256, 0, stream>>>(X, Y, N, M, sPong, sPong + N);

  // input staged in `pong`; after 3 passes sorted result is in `ping`
  auto sortJob = [&](unsigned* ping, unsigned* pong, int segs, int L) {
    int T = (L + TILE - 1) / TILE;
    unsigned* s = pong;
    unsigned* d = ping;
    for (int p = 0; p < NPASS; ++p) {
      int shift = 8 * (p + 1);
      k_hist8<<<dim3(T, segs), 256, 0, stream>>>(s, L, T, shift, counts8);
      k_scan64<<<segs, 64, 0, stream>>>(counts8, 256 * T);
      k_scatter8<<<dim3(T, segs), 256, 0, stream>>>(s, d, L, T, shift, counts8);
      unsigned* t = s; s = d; d = t;
    }
  };

  if (N == M) sortJob(sPing, sPong, 2, N);
  else { sortJob(sPing, sPong, 1, N); sortJob(sPing + N, sPong + N, 1, M); }

  for (int k0 = 0; k0 < KDIR; k0 += Kc) {
    int kc = (KDIR - k0 < Kc) ? (KDIR - k0) : Kc;
    unsigned* pXin = cPong;
    unsigned* pYin = cPong + (size_t)kc * N;
    unsigned* pX = cPing;
    unsigned* pY = cPing + (size_t)kc * N;
    k_buildProj<<<dim3((N + 255) / 256, kc), 256, 0, stream>>>(X, N, k0, tbl, pXin);
    k_buildProj<<<dim3((M + 255) / 256, kc), 256, 0, stream>>>(Y, M, k0, tbl, pYin);
    if (N == M) sortJob(cPing, cPong, 2 * kc, N);
    else { sortJob(pX, pXin, kc, N); sortJob(pY, pYin, kc, M); }
    int Stot = N + M;
    int mBlocks = (Stot + MOUT - 1) / MOUT;
    k_merge<<<dim3(mBlocks, kc), MBLK, 0, stream>>>(pX, pY, sPing, sPing + N, N, M, k0, tbl, accum);
  }
  k_final<<<1, 1, 0, stream>>>(accum, (float*)d_out);
}

// Round 6
// 1193.965 us; speedup vs baseline: 2.8261x; 1.7137x over previous
//
#include <hip/hip_runtime.h>

#define KDIR 100
#define TILE 4096
#define NPASS 3
#define MBLK 256
#define MOUT 4096
#define MPT2 (MOUT / MBLK)

__device__ __forceinline__ unsigned encodeF(float f) {
  unsigned u = __float_as_uint(f);
  return u ^ ((u >> 31) ? 0xFFFFFFFFu : 0x80000000u);
}
__device__ __forceinline__ float decodeU(unsigned u) {
  return __uint_as_float(u ^ ((u >> 31) ? 0x80000000u : 0xFFFFFFFFu));
}

// tbl layout: [0..99]=cos, [128..227]=sin, [256..355]=c=(cos+sin)*invn, [384..483]=invn
// synthetic entry k=100: (0.5, 0.5, invn=1) -> diagonal key 0.5*(x+y)
__global__ void k_table(float* tbl, double* accum) {
  int k = threadIdx.x;
  const double PI = 3.14159265358979323846;
  if (k < KDIR) {
    double th = -PI * 0.5 + (double)k * (PI / (double)KDIR);
    float c = (float)cos(th), s = (float)sin(th);
    float invn = 1.0f / (c * c + s * s);
    tbl[k] = c; tbl[128 + k] = s; tbl[256 + k] = (c + s) * invn; tbl[384 + k] = invn;
  }
  if (k == 100) { tbl[100] = 0.5f; tbl[228] = 0.5f; tbl[484] = 1.0f; }
  if (k == 0) *accum = 0.0;
}

// Fused projection-build + pass-0 (shift=8) per-tile histogram.
// counts[((seg0+dir)*256 + d)*T + tile]
__global__ __launch_bounds__(256) void k_build(const float* __restrict__ P, int n, int kIdx,
                                               const float* __restrict__ tbl,
                                               unsigned* __restrict__ dst,
                                               unsigned* __restrict__ counts, int T, int seg0) {
  __shared__ unsigned h[256];
  int tid = threadIdx.x;
  h[tid] = 0;
  __syncthreads();
  int dir = blockIdx.y;
  int k = kIdx + dir;
  float ck = tbl[k], sk = tbl[128 + k], inv = tbl[384 + k];
  int tile = blockIdx.x;
  int start = tile * TILE;
  int nItems = min(TILE, n - start);
  unsigned* d0 = dst + (size_t)dir * n + start;
  const float* p0 = P + 2 * (size_t)start;
  if (nItems == TILE) {
    const float4* p4 = (const float4*)p0;
    uint2* o2 = (uint2*)d0;
#pragma unroll
    for (int i = 0; i < 8; ++i) {
      float4 v = p4[i * 256 + tid];
      unsigned ua = encodeF((v.x * ck + v.y * sk) * inv);
      unsigned ub = encodeF((v.z * ck + v.w * sk) * inv);
      o2[i * 256 + tid] = make_uint2(ua, ub);
      atomicAdd(&h[(ua >> 8) & 255u], 1u);
      atomicAdd(&h[(ub >> 8) & 255u], 1u);
    }
  } else {
    for (int j = tid; j < nItems; j += 256) {
      float x = p0[2 * j], y = p0[2 * j + 1];
      unsigned u = encodeF((x * ck + y * sk) * inv);
      d0[j] = u;
      atomicAdd(&h[(u >> 8) & 255u], 1u);
    }
  }
  __syncthreads();
  counts[((size_t)(seg0 + dir) * 256 + tid) * T + tile] = h[tid];
}

// Per-pass 8-bit histogram (passes 1,2) on the current pass input (order-invariant).
__global__ __launch_bounds__(256) void k_hist8(const unsigned* __restrict__ keys,
                                               int L, int T, int shift,
                                               unsigned* __restrict__ counts) {
  __shared__ unsigned h[256];
  int tid = threadIdx.x;
  h[tid] = 0;
  __syncthreads();
  int seg = blockIdx.y, tile = blockIdx.x;
  const unsigned* base = keys + (size_t)seg * L + (size_t)tile * TILE;
  int nItems = min(TILE, L - tile * TILE);
  if (nItems == TILE) {
    const uint4* b4 = (const uint4*)base;
#pragma unroll
    for (int i = 0; i < 4; ++i) {
      uint4 v = b4[i * 256 + tid];
      atomicAdd(&h[(v.x >> shift) & 255u], 1u);
      atomicAdd(&h[(v.y >> shift) & 255u], 1u);
      atomicAdd(&h[(v.z >> shift) & 255u], 1u);
      atomicAdd(&h[(v.w >> shift) & 255u], 1u);
    }
  } else {
    for (int i = tid; i < nItems; i += 256)
      atomicAdd(&h[(base[i] >> shift) & 255u], 1u);
  }
  __syncthreads();
  counts[((size_t)seg * 256 + tid) * T + tile] = h[tid];
}

// Per-segment exclusive scan of [256*T] (digit-major): 256 threads, T elems each.
__global__ __launch_bounds__(256) void k_scanSeg(unsigned* __restrict__ counts, int T) {
  __shared__ unsigned tot[256];
  unsigned* c = counts + (size_t)blockIdx.x * 256 * T;
  int tid = threadIdx.x;
  int base = tid * T;
  unsigned sum = 0;
  for (int i = 0; i < T; ++i) sum += c[base + i];
  tot[tid] = sum;
  __syncthreads();
  for (int ofs = 1; ofs < 256; ofs <<= 1) {
    unsigned t = (tid >= ofs) ? tot[tid - ofs] : 0u;
    __syncthreads();
    tot[tid] += t;
    __syncthreads();
  }
  unsigned run = tot[tid] - sum;  // exclusive prefix of this thread's chunk
  for (int i = 0; i < T; ++i) {
    unsigned v = c[base + i];
    c[base + i] = run;
    run += v;
  }
}

// 8-bit scatter, STABLE: each wave owns a contiguous quarter of the tile;
// within a wave, i-steps ascend and lane order = item order; rank via
// ballot digit-group isolation + leader-updated per-wave LDS counter.
// Keys/ranks in registers; LDS = 4 KB only.
__global__ __launch_bounds__(256) void k_scatter8(const unsigned* __restrict__ src,
                                                  unsigned* __restrict__ dst,
                                                  int L, int T, int shift,
                                                  const unsigned* __restrict__ counts) {
  __shared__ unsigned runW[4][256];  // per-wave digit counters, then folded bases
  int tid = threadIdx.x;
  int lane = tid & 63, w = tid >> 6;
  int seg = blockIdx.y, tile = blockIdx.x;
  const unsigned* sbase = src + (size_t)seg * L + (size_t)tile * TILE;
  int nItems = min(TILE, L - tile * TILE);
  for (int i = tid; i < 4 * 256; i += 256) ((unsigned*)runW)[i] = 0;
  __syncthreads();
  unsigned kk[16];
  unsigned rr[16];
  unsigned long long laneLT = (1ull << lane) - 1ull;
  int jbase = w * (TILE / 4);
#pragma unroll
  for (int i = 0; i < 16; ++i) {
    int j = jbase + i * 64 + lane;
    bool valid = j < nItems;
    unsigned long long act = __ballot(valid);
    if (valid) {
      unsigned k = sbase[j];
      kk[i] = k;
      unsigned d = (k >> shift) & 255u;
      unsigned long long mask = act;
#pragma unroll
      for (int b = 0; b < 8; ++b) {
        unsigned long long bal = __ballot((d >> b) & 1);
        mask &= ((d >> b) & 1) ? bal : ~bal;
      }
      unsigned r = (unsigned)__popcll(mask & laneLT);
      unsigned prev = runW[w][d];            // broadcast within digit group
      rr[i] = prev + r;
      if (r == 0) runW[w][d] = prev + (unsigned)__popcll(mask);  // leader
    }
  }
  __syncthreads();
  // fold global digit base (scanned counts) + cross-wave prefix into runW
  {
    unsigned s = counts[((size_t)seg * 256 + tid) * T + tile];
#pragma unroll
    for (int ww = 0; ww < 4; ++ww) {
      unsigned t = runW[ww][tid];
      runW[ww][tid] = s;
      s += t;
    }
  }
  __syncthreads();
  unsigned* dbase = dst + (size_t)seg * L;
#pragma unroll
  for (int i = 0; i < 16; ++i) {
    int j = jbase + i * 64 + lane;
    if (j < nItems) {
      unsigned d = (kk[i] >> shift) & 255u;
      dbase[runW[w][d] + rr[i]] = kk[i];
    }
  }
}

__device__ __forceinline__ float scaledAt(const unsigned* __restrict__ s, int len, int j,
                                          float c, int rev) {
  return c * decodeU(s[rev ? (len - 1 - j) : j]);
}

__device__ int mergeSplit(const unsigned* __restrict__ U, int n,
                          const unsigned* __restrict__ sV, int m,
                          float c, int rev, int o) {
  int lo = o - m; if (lo < 0) lo = 0;
  int hi = o < n ? o : n;
  while (lo < hi) {
    int mid = (lo + hi + 1) >> 1;
    if (decodeU(U[mid - 1]) <= scaledAt(sV, m, o - mid, c, rev)) lo = mid;
    else hi = mid - 1;
  }
  return lo;
}

__device__ __forceinline__ int ldsSplit(const float* __restrict__ a, int n,
                                        const float* __restrict__ b, int m, int o) {
  int lo = o - m; if (lo < 0) lo = 0;
  int hi = o < n ? o : n;
  while (lo < hi) {
    int mid = (lo + hi + 1) >> 1;
    if (a[mid - 1] <= b[o - mid]) lo = mid;
    else hi = mid - 1;
  }
  return lo;
}

__global__ __launch_bounds__(MBLK) void k_merge(const unsigned* __restrict__ pX,
                                                const unsigned* __restrict__ pY,
                                                const unsigned* __restrict__ sx,
                                                const unsigned* __restrict__ sy,
                                                int N, int M, int k0,
                                                const float* __restrict__ tbl,
                                                double* __restrict__ accum) {
  const float FMAX = 3.402823466e38f;
  __shared__ float sA[MOUT];
  __shared__ float sB[MOUT];
  __shared__ int splits[4];
  __shared__ float red[MBLK];
  int kl = blockIdx.y;
  float c = tbl[256 + k0 + kl];
  int rev = c < 0.0f ? 1 : 0;
  int Stot = N + M;
  int o0 = blockIdx.x * MOUT;
  int outCnt = min(MOUT, Stot - o0);
  const unsigned* U1 = pX + (size_t)kl * N;
  const unsigned* U2 = pY + (size_t)kl * M;
  int tid = threadIdx.x;
  if (tid == 0)        splits[0] = mergeSplit(U1, N, sy, M, c, rev, o0);
  else if (tid == 64)  splits[1] = mergeSplit(U1, N, sy, M, c, rev, o0 + outCnt);
  else if (tid == 128) splits[2] = mergeSplit(U2, M, sx, N, c, rev, o0);
  else if (tid == 192) splits[3] = mergeSplit(U2, M, sx, N, c, rev, o0 + outCnt);
  __syncthreads();
  int aLo = splits[0], aCnt = splits[1] - aLo;
  int bLo = o0 - aLo, bCnt = outCnt - aCnt;
  int a2Lo = splits[2], a2Cnt = splits[3] - a2Lo;
  int b2Lo = o0 - a2Lo, b2Cnt = outCnt - a2Cnt;
  for (int i = tid; i < aCnt; i += MBLK) sA[i] = decodeU(U1[aLo + i]);
  for (int i = tid; i < bCnt; i += MBLK) {
    int j = bLo + i;
    sA[aCnt + i] = c * decodeU(sy[rev ? (M - 1 - j) : j]);
  }
  for (int i = tid; i < a2Cnt; i += MBLK) sB[i] = decodeU(U2[a2Lo + i]);
  for (int i = tid; i < b2Cnt; i += MBLK) {
    int j = b2Lo + i;
    sB[a2Cnt + i] = c * decodeU(sx[rev ? (N - 1 - j) : j]);
  }
  __syncthreads();
  float acc = 0.0f;
  int lo0 = tid * MPT2;
  if (lo0 < outCnt) {
    int cnt = min(MPT2, outCnt - lo0);
    int la = ldsSplit(sA, aCnt, sA + aCnt, bCnt, lo0);
    int lb = lo0 - la;
    int la2 = ldsSplit(sB, a2Cnt, sB + a2Cnt, b2Cnt, lo0);
    int lb2 = lo0 - la2;
    float u1 = la < aCnt ? sA[la] : FMAX;
    float v1 = lb < bCnt ? sA[aCnt + lb] : FMAX;
    float u2 = la2 < a2Cnt ? sB[la2] : FMAX;
    float v2 = lb2 < b2Cnt ? sB[a2Cnt + lb2] : FMAX;
    for (int s = 0; s < cnt; ++s) {
      float Av, Bv;
      if (u1 <= v1) { Av = u1; ++la; u1 = la < aCnt ? sA[la] : FMAX; }
      else          { Av = v1; ++lb; v1 = lb < bCnt ? sA[aCnt + lb] : FMAX; }
      if (u2 <= v2) { Bv = u2; ++la2; u2 = la2 < a2Cnt ? sB[la2] : FMAX; }
      else          { Bv = v2; ++lb2; v2 = lb2 < b2Cnt ? sB[a2Cnt + lb2] : FMAX; }
      acc += fabsf(Av - Bv);
    }
  }
  red[tid] = acc;
  __syncthreads();
  for (int ofs = MBLK / 2; ofs > 0; ofs >>= 1) {
    if (tid < ofs) red[tid] += red[tid + ofs];
    __syncthreads();
  }
  if (tid == 0) atomicAdd(accum, (double)red[0]);
}

__global__ void k_final(const double* __restrict__ accum, float* __restrict__ out) {
  out[0] = (float)(*accum / (double)KDIR);
}

extern "C" void kernel_launch(void* const* d_in, const int* in_sizes, int n_in,
                              void* d_out, int out_size, void* d_ws, size_t ws_size,
                              hipStream_t stream) {
  const float* X = (const float*)d_in[0];
  const float* Y = (const float*)d_in[1];
  int N = in_sizes[0] / 2;
  int M = in_sizes[1] / 2;

  char* ws = (char*)d_ws;
  size_t off = 0;
  auto alloc = [&](size_t b) -> void* {
    void* p = ws + off;
    off += (b + 255) & ~(size_t)255;
    return p;
  };
  float* tbl = (float*)alloc(512 * sizeof(float));
  double* accum = (double*)alloc(256);
  unsigned* sPing = (unsigned*)alloc((size_t)(N + M) * 4);
  unsigned* sPong = (unsigned*)alloc((size_t)(N + M) * 4);

  int Tn = (N + TILE - 1) / TILE;
  int Tm = (M + TILE - 1) / TILE;
  int Tmax = Tn > Tm ? Tn : Tm;

  // per direction: ping+pong keys (2 segs) + counts (2 segs x 256 x Tmax)
  size_t perDir = (size_t)(N + M) * 8 + (size_t)2 * 256 * Tmax * 4;
  size_t remain = ws_size > off ? ws_size - off : 0;
  int Kc = (int)(remain / perDir);
  if (Kc > KDIR) Kc = KDIR;
  if (Kc < 1) Kc = 1;
  int maxSegs = 2 * Kc;
  unsigned* counts8 = (unsigned*)alloc((size_t)maxSegs * 256 * Tmax * 4);
  unsigned* cPing = (unsigned*)alloc((size_t)Kc * (size_t)(N + M) * 4);
  unsigned* cPong = (unsigned*)alloc((size_t)Kc * (size_t)(N + M) * 4);

  k_table<<<1, 128, 0, stream>>>(tbl, accum);

  // pass-0 counts are prefilled by k_build; passes 1,2 run k_hist8.
  // input staged in `pong`; after 3 (odd) passes sorted result lands in `ping`.
  auto sortJob = [&](unsigned* ping, unsigned* pong, int segs, int L) {
    int T = (L + TILE - 1) / TILE;
    unsigned* s = pong;
    unsigned* d = ping;
    for (int p = 0; p < NPASS; ++p) {
      int shift = 8 * (p + 1);
      if (p > 0)
        k_hist8<<<dim3(T, segs), 256, 0, stream>>>(s, L, T, shift, counts8);
      k_scanSeg<<<segs, 256, 0, stream>>>(counts8, T);
      k_scatter8<<<dim3(T, segs), 256, 0, stream>>>(s, d, L, T, shift, counts8);
      unsigned* t = s; s = d; d = t;
    }
  };

  // diagonal keys: k=100 synthetic direction (0.5, 0.5, invn=1)
  if (N == M) {
    k_build<<<dim3(Tn, 1), 256, 0, stream>>>(X, N, 100, tbl, sPong, counts8, Tn, 0);
    k_build<<<dim3(Tn, 1), 256, 0, stream>>>(Y, N, 100, tbl, sPong + N, counts8, Tn, 1);
    sortJob(sPing, sPong, 2, N);
  } else {
    k_build<<<dim3(Tn, 1), 256, 0, stream>>>(X, N, 100, tbl, sPong, counts8, Tn, 0);
    sortJob(sPing, sPong, 1, N);
    k_build<<<dim3(Tm, 1), 256, 0, stream>>>(Y, M, 100, tbl, sPong + N, counts8, Tm, 0);
    sortJob(sPing + N, sPong + N, 1, M);
  }

  for (int k0 = 0; k0 < KDIR; k0 += Kc) {
    int kc = (KDIR - k0 < Kc) ? (KDIR - k0) : Kc;
    unsigned* pXin = cPong;
    unsigned* pYin = cPong + (size_t)kc * N;
    unsigned* pX = cPing;
    unsigned* pY = cPing + (size_t)kc * N;
    if (N == M) {
      k_build<<<dim3(Tn, kc), 256, 0, stream>>>(X, N, k0, tbl, pXin, counts8, Tn, 0);
      k_build<<<dim3(Tn, kc), 256, 0, stream>>>(Y, N, k0, tbl, pYin, counts8, Tn, kc);
      sortJob(cPing, cPong, 2 * kc, N);
    } else {
      k_build<<<dim3(Tn, kc), 256, 0, stream>>>(X, N, k0, tbl, pXin, counts8, Tn, 0);
      sortJob(pX, pXin, kc, N);
      k_build<<<dim3(Tm, kc), 256, 0, stream>>>(Y, M, k0, tbl, pYin, counts8, Tm, 0);
      sortJob(pY, pYin, kc, M);
    }
    int Stot = N + M;
    int mBlocks = (Stot + MOUT - 1) / MOUT;
    k_merge<<<dim3(mBlocks, kc), MBLK, 0, stream>>>(pX, pY, sPing, sPing + N, N, M, k0, tbl, accum);
  }
  k_final<<<1, 1, 0, stream>>>(accum, (float*)d_out);
}

// Round 7
// 1154.211 us; speedup vs baseline: 2.9234x; 1.0344x over previous
//
#include <hip/hip_runtime.h>

#define KDIR 100
#define TILE 4096
#define NPASS 3
#define MBLK 256
#define MOUT 4096
#define MPT2 (MOUT / MBLK)

__device__ __forceinline__ unsigned encodeF(float f) {
  unsigned u = __float_as_uint(f);
  return u ^ ((u >> 31) ? 0xFFFFFFFFu : 0x80000000u);
}
__device__ __forceinline__ float decodeU(unsigned u) {
  return __uint_as_float(u ^ ((u >> 31) ? 0x80000000u : 0xFFFFFFFFu));
}

// tbl layout: [0..99]=cos, [128..227]=sin, [256..355]=c=(cos+sin)*invn, [384..483]=invn
// synthetic entry k=100: (0.5, 0.5, invn=1) -> diagonal key 0.5*(x+y)
__global__ void k_table(float* tbl, double* accum) {
  int k = threadIdx.x;
  const double PI = 3.14159265358979323846;
  if (k < KDIR) {
    double th = -PI * 0.5 + (double)k * (PI / (double)KDIR);
    float c = (float)cos(th), s = (float)sin(th);
    float invn = 1.0f / (c * c + s * s);
    tbl[k] = c; tbl[128 + k] = s; tbl[256 + k] = (c + s) * invn; tbl[384 + k] = invn;
  }
  if (k == 100) { tbl[100] = 0.5f; tbl[228] = 0.5f; tbl[484] = 1.0f; }
  if (k == 0) *accum = 0.0;
}

// Fused projection-build + pass-0 (shift=8) per-tile histogram.
// counts[((seg0+dir)*256 + d)*T + tile]
__global__ __launch_bounds__(256) void k_build(const float* __restrict__ P, int n, int kIdx,
                                               const float* __restrict__ tbl,
                                               unsigned* __restrict__ dst,
                                               unsigned* __restrict__ counts, int T, int seg0) {
  __shared__ unsigned h[256];
  int tid = threadIdx.x;
  h[tid] = 0;
  __syncthreads();
  int dir = blockIdx.y;
  int k = kIdx + dir;
  float ck = tbl[k], sk = tbl[128 + k], inv = tbl[384 + k];
  int tile = blockIdx.x;
  int start = tile * TILE;
  int nItems = min(TILE, n - start);
  unsigned* d0 = dst + (size_t)dir * n + start;
  const float* p0 = P + 2 * (size_t)start;
  if (nItems == TILE) {
    const float4* p4 = (const float4*)p0;
    uint2* o2 = (uint2*)d0;
#pragma unroll
    for (int i = 0; i < 8; ++i) {
      float4 v = p4[i * 256 + tid];
      unsigned ua = encodeF((v.x * ck + v.y * sk) * inv);
      unsigned ub = encodeF((v.z * ck + v.w * sk) * inv);
      o2[i * 256 + tid] = make_uint2(ua, ub);
      atomicAdd(&h[(ua >> 8) & 255u], 1u);
      atomicAdd(&h[(ub >> 8) & 255u], 1u);
    }
  } else {
    for (int j = tid; j < nItems; j += 256) {
      float x = p0[2 * j], y = p0[2 * j + 1];
      unsigned u = encodeF((x * ck + y * sk) * inv);
      d0[j] = u;
      atomicAdd(&h[(u >> 8) & 255u], 1u);
    }
  }
  __syncthreads();
  counts[((size_t)(seg0 + dir) * 256 + tid) * T + tile] = h[tid];
}

// Per-pass 8-bit histogram (passes 1,2) on the current pass input (order-invariant).
__global__ __launch_bounds__(256) void k_hist8(const unsigned* __restrict__ keys,
                                               int L, int T, int shift,
                                               unsigned* __restrict__ counts) {
  __shared__ unsigned h[256];
  int tid = threadIdx.x;
  h[tid] = 0;
  __syncthreads();
  int seg = blockIdx.y, tile = blockIdx.x;
  const unsigned* base = keys + (size_t)seg * L + (size_t)tile * TILE;
  int nItems = min(TILE, L - tile * TILE);
  if (nItems == TILE) {
    const uint4* b4 = (const uint4*)base;
#pragma unroll
    for (int i = 0; i < 4; ++i) {
      uint4 v = b4[i * 256 + tid];
      atomicAdd(&h[(v.x >> shift) & 255u], 1u);
      atomicAdd(&h[(v.y >> shift) & 255u], 1u);
      atomicAdd(&h[(v.z >> shift) & 255u], 1u);
      atomicAdd(&h[(v.w >> shift) & 255u], 1u);
    }
  } else {
    for (int i = tid; i < nItems; i += 256)
      atomicAdd(&h[(base[i] >> shift) & 255u], 1u);
  }
  __syncthreads();
  counts[((size_t)seg * 256 + tid) * T + tile] = h[tid];
}

// Per-segment exclusive scan of [256*T] (digit-major): 256 threads, T elems each.
__global__ __launch_bounds__(256) void k_scanSeg(unsigned* __restrict__ counts, int T) {
  __shared__ unsigned tot[256];
  unsigned* c = counts + (size_t)blockIdx.x * 256 * T;
  int tid = threadIdx.x;
  int base = tid * T;
  unsigned sum = 0;
  for (int i = 0; i < T; ++i) sum += c[base + i];
  tot[tid] = sum;
  __syncthreads();
  for (int ofs = 1; ofs < 256; ofs <<= 1) {
    unsigned t = (tid >= ofs) ? tot[tid - ofs] : 0u;
    __syncthreads();
    tot[tid] += t;
    __syncthreads();
  }
  unsigned run = tot[tid] - sum;  // exclusive prefix of this thread's chunk
  for (int i = 0; i < T; ++i) {
    unsigned v = c[base + i];
    c[base + i] = run;
    run += v;
  }
}

// 8-bit scatter, STABLE, with 4 independent per-wave ranking chains.
// Wave w owns contiguous quarter; group g owns items i in [4g, 4g+4);
// loop s-outer/g-inner so the 4 chains' LDS round-trips overlap.
// Order = (w, g, s, lane) == tile position order; fold is w-major, g-minor.
__global__ __launch_bounds__(256) void k_scatter8(const unsigned* __restrict__ src,
                                                  unsigned* __restrict__ dst,
                                                  int L, int T, int shift,
                                                  const unsigned* __restrict__ counts) {
  __shared__ unsigned runG[4][4][256];  // [wave][group][digit], 16 KB
  int tid = threadIdx.x;
  int lane = tid & 63, w = tid >> 6;
  int seg = blockIdx.y, tile = blockIdx.x;
  const unsigned* sbase = src + (size_t)seg * L + (size_t)tile * TILE;
  int nItems = min(TILE, L - tile * TILE);
  for (int i = tid; i < 4 * 4 * 256; i += 256) ((unsigned*)runG)[i] = 0;
  __syncthreads();
  unsigned kk[16];
  unsigned rr[16];
  unsigned long long laneLT = (1ull << lane) - 1ull;
  int jbase = w * (TILE / 4);
#pragma unroll
  for (int i = 0; i < 16; ++i) {
    int j = jbase + i * 64 + lane;
    kk[i] = (j < nItems) ? sbase[j] : 0xFFFFFFFFu;
  }
#pragma unroll
  for (int s = 0; s < 4; ++s) {
    unsigned long long mask[4];
    unsigned prev[4];
    // phase 1: ballot-isolate digit groups (VALU only), issue the 4 reads
#pragma unroll
    for (int g = 0; g < 4; ++g) {
      int i = g * 4 + s;
      int j = jbase + i * 64 + lane;
      bool valid = j < nItems;
      unsigned long long act = __ballot(valid);
      unsigned d = (kk[i] >> shift) & 255u;
      unsigned long long m = act;
#pragma unroll
      for (int b = 0; b < 8; ++b) {
        unsigned long long bal = __ballot((d >> b) & 1);
        m &= ((d >> b) & 1) ? bal : ~bal;
      }
      mask[g] = m;
      prev[g] = runG[w][g][d];     // ds_read; use deferred to phase 2
    }
    // phase 2: ranks + leader write-back (4 independent chains)
#pragma unroll
    for (int g = 0; g < 4; ++g) {
      int i = g * 4 + s;
      int j = jbase + i * 64 + lane;
      if (j < nItems) {
        unsigned d = (kk[i] >> shift) & 255u;
        unsigned r = (unsigned)__popcll(mask[g] & laneLT);
        rr[i] = prev[g] + r;
        if (r == 0) runG[w][g][d] = prev[g] + (unsigned)__popcll(mask[g]);
      }
    }
  }
  __syncthreads();
  // fold global digit base + cross-(wave,group) prefix into runG (w-major, g-minor)
  {
    unsigned run = counts[((size_t)seg * 256 + tid) * T + tile];
#pragma unroll
    for (int w2 = 0; w2 < 4; ++w2)
#pragma unroll
      for (int g2 = 0; g2 < 4; ++g2) {
        unsigned t = runG[w2][g2][tid];
        runG[w2][g2][tid] = run;
        run += t;
      }
  }
  __syncthreads();
  unsigned* dbase = dst + (size_t)seg * L;
#pragma unroll
  for (int i = 0; i < 16; ++i) {
    int j = jbase + i * 64 + lane;
    if (j < nItems) {
      unsigned d = (kk[i] >> shift) & 255u;
      dbase[runG[w][i >> 2][d] + rr[i]] = kk[i];
    }
  }
}

__device__ __forceinline__ float scaledAt(const unsigned* __restrict__ s, int len, int j,
                                          float c, int rev) {
  return c * decodeU(s[rev ? (len - 1 - j) : j]);
}

__device__ int mergeSplit(const unsigned* __restrict__ U, int n,
                          const unsigned* __restrict__ sV, int m,
                          float c, int rev, int o) {
  int lo = o - m; if (lo < 0) lo = 0;
  int hi = o < n ? o : n;
  while (lo < hi) {
    int mid = (lo + hi + 1) >> 1;
    if (decodeU(U[mid - 1]) <= scaledAt(sV, m, o - mid, c, rev)) lo = mid;
    else hi = mid - 1;
  }
  return lo;
}

__device__ __forceinline__ int ldsSplit(const float* __restrict__ a, int n,
                                        const float* __restrict__ b, int m, int o) {
  int lo = o - m; if (lo < 0) lo = 0;
  int hi = o < n ? o : n;
  while (lo < hi) {
    int mid = (lo + hi + 1) >> 1;
    if (a[mid - 1] <= b[o - mid]) lo = mid;
    else hi = mid - 1;
  }
  return lo;
}

__global__ __launch_bounds__(MBLK) void k_merge(const unsigned* __restrict__ pX,
                                                const unsigned* __restrict__ pY,
                                                const unsigned* __restrict__ sx,
                                                const unsigned* __restrict__ sy,
                                                int N, int M, int k0,
                                                const float* __restrict__ tbl,
                                                double* __restrict__ accum) {
  const float FMAX = 3.402823466e38f;
  __shared__ float sA[MOUT];
  __shared__ float sB[MOUT];
  __shared__ int splits[4];
  __shared__ float red[MBLK];
  int kl = blockIdx.y;
  float c = tbl[256 + k0 + kl];
  int rev = c < 0.0f ? 1 : 0;
  int Stot = N + M;
  int o0 = blockIdx.x * MOUT;
  int outCnt = min(MOUT, Stot - o0);
  const unsigned* U1 = pX + (size_t)kl * N;
  const unsigned* U2 = pY + (size_t)kl * M;
  int tid = threadIdx.x;
  if (tid == 0)        splits[0] = mergeSplit(U1, N, sy, M, c, rev, o0);
  else if (tid == 64)  splits[1] = mergeSplit(U1, N, sy, M, c, rev, o0 + outCnt);
  else if (tid == 128) splits[2] = mergeSplit(U2, M, sx, N, c, rev, o0);
  else if (tid == 192) splits[3] = mergeSplit(U2, M, sx, N, c, rev, o0 + outCnt);
  __syncthreads();
  int aLo = splits[0], aCnt = splits[1] - aLo;
  int bLo = o0 - aLo, bCnt = outCnt - aCnt;
  int a2Lo = splits[2], a2Cnt = splits[3] - a2Lo;
  int b2Lo = o0 - a2Lo, b2Cnt = outCnt - a2Cnt;
  for (int i = tid; i < aCnt; i += MBLK) sA[i] = decodeU(U1[aLo + i]);
  for (int i = tid; i < bCnt; i += MBLK) {
    int j = bLo + i;
    sA[aCnt + i] = c * decodeU(sy[rev ? (M - 1 - j) : j]);
  }
  for (int i = tid; i < a2Cnt; i += MBLK) sB[i] = decodeU(U2[a2Lo + i]);
  for (int i = tid; i < b2Cnt; i += MBLK) {
    int j = b2Lo + i;
    sB[a2Cnt + i] = c * decodeU(sx[rev ? (N - 1 - j) : j]);
  }
  __syncthreads();
  float acc = 0.0f;
  int lo0 = tid * MPT2;
  if (lo0 < outCnt) {
    int cnt = min(MPT2, outCnt - lo0);
    int la = ldsSplit(sA, aCnt, sA + aCnt, bCnt, lo0);
    int lb = lo0 - la;
    int la2 = ldsSplit(sB, a2Cnt, sB + a2Cnt, b2Cnt, lo0);
    int lb2 = lo0 - la2;
    float u1 = la < aCnt ? sA[la] : FMAX;
    float v1 = lb < bCnt ? sA[aCnt + lb] : FMAX;
    float u2 = la2 < a2Cnt ? sB[la2] : FMAX;
    float v2 = lb2 < b2Cnt ? sB[a2Cnt + lb2] : FMAX;
    for (int s = 0; s < cnt; ++s) {
      float Av, Bv;
      if (u1 <= v1) { Av = u1; ++la; u1 = la < aCnt ? sA[la] : FMAX; }
      else          { Av = v1; ++lb; v1 = lb < bCnt ? sA[aCnt + lb] : FMAX; }
      if (u2 <= v2) { Bv = u2; ++la2; u2 = la2 < a2Cnt ? sB[la2] : FMAX; }
      else          { Bv = v2; ++lb2; v2 = lb2 < b2Cnt ? sB[a2Cnt + lb2] : FMAX; }
      acc += fabsf(Av - Bv);
    }
  }
  red[tid] = acc;
  __syncthreads();
  for (int ofs = MBLK / 2; ofs > 0; ofs >>= 1) {
    if (tid < ofs) red[tid] += red[tid + ofs];
    __syncthreads();
  }
  if (tid == 0) atomicAdd(accum, (double)red[0]);
}

__global__ void k_final(const double* __restrict__ accum, float* __restrict__ out) {
  out[0] = (float)(*accum / (double)KDIR);
}

extern "C" void kernel_launch(void* const* d_in, const int* in_sizes, int n_in,
                              void* d_out, int out_size, void* d_ws, size_t ws_size,
                              hipStream_t stream) {
  const float* X = (const float*)d_in[0];
  const float* Y = (const float*)d_in[1];
  int N = in_sizes[0] / 2;
  int M = in_sizes[1] / 2;

  char* ws = (char*)d_ws;
  size_t off = 0;
  auto alloc = [&](size_t b) -> void* {
    void* p = ws + off;
    off += (b + 255) & ~(size_t)255;
    return p;
  };
  float* tbl = (float*)alloc(512 * sizeof(float));
  double* accum = (double*)alloc(256);
  unsigned* sPing = (unsigned*)alloc((size_t)(N + M) * 4);
  unsigned* sPong = (unsigned*)alloc((size_t)(N + M) * 4);

  int Tn = (N + TILE - 1) / TILE;
  int Tm = (M + TILE - 1) / TILE;
  int Tmax = Tn > Tm ? Tn : Tm;
  int mx = N > M ? N : M;

  // per direction: ping+pong keys (2 segs) + counts (2 segs x 256 x Tmax);
  // reserve 2 extra segment rows (fused diagonal sort).
  size_t perDir = (size_t)(N + M) * 8 + (size_t)2 * 256 * Tmax * 4;
  size_t reserve = (size_t)2 * mx * 8 + (size_t)2 * 256 * Tmax * 4;
  size_t remain = ws_size > off ? ws_size - off : 0;
  remain = remain > reserve ? remain - reserve : 0;
  int Kc = (int)(remain / perDir);
  if (Kc > KDIR) Kc = KDIR;
  if (Kc < 1) Kc = 1;
  int maxSegs = 2 * Kc + 2;
  unsigned* counts8 = (unsigned*)alloc((size_t)maxSegs * 256 * Tmax * 4);
  unsigned* cPing = (unsigned*)alloc(((size_t)Kc * (N + M) + 2 * (size_t)mx) * 4);
  unsigned* cPong = (unsigned*)alloc(((size_t)Kc * (N + M) + 2 * (size_t)mx) * 4);

  k_table<<<1, 128, 0, stream>>>(tbl, accum);

  // pass-0 counts are prefilled by k_build; passes 1,2 run k_hist8.
  // input staged in `pong`; after 3 (odd) passes sorted result lands in `ping`.
  auto sortJob = [&](unsigned* ping, unsigned* pong, int segs, int L) {
    int T = (L + TILE - 1) / TILE;
    unsigned* s = pong;
    unsigned* d = ping;
    for (int p = 0; p < NPASS; ++p) {
      int shift = 8 * (p + 1);
      if (p > 0)
        k_hist8<<<dim3(T, segs), 256, 0, stream>>>(s, L, T, shift, counts8);
      k_scanSeg<<<segs, 256, 0, stream>>>(counts8, T);
      k_scatter8<<<dim3(T, segs), 256, 0, stream>>>(s, d, L, T, shift, counts8);
      unsigned* t = s; s = d; d = t;
    }
  };

  bool fused = (N == M) && (Kc == KDIR);

  if (fused) {
    // single 202-segment sort: [0..99]=projX dirs, [100..199]=projY dirs,
    // [200]=diagX, [201]=diagY. All segments length N.
    unsigned* dXin = cPong + (size_t)2 * KDIR * N;
    unsigned* dYin = dXin + N;
    k_build<<<dim3(Tn, KDIR), 256, 0, stream>>>(X, N, 0, tbl, cPong, counts8, Tn, 0);
    k_build<<<dim3(Tn, KDIR), 256, 0, stream>>>(Y, N, 0, tbl, cPong + (size_t)KDIR * N,
                                                counts8, Tn, KDIR);
    k_build<<<dim3(Tn, 1), 256, 0, stream>>>(X, N, 100, tbl, dXin, counts8, Tn, 2 * KDIR);
    k_build<<<dim3(Tn, 1), 256, 0, stream>>>(Y, N, 100, tbl, dYin, counts8, Tn, 2 * KDIR + 1);
    sortJob(cPing, cPong, 2 * KDIR + 2, N);
    unsigned* pX = cPing;
    unsigned* pY = cPing + (size_t)KDIR * N;
    unsigned* dX = cPing + (size_t)2 * KDIR * N;
    unsigned* dY = dX + N;
    int Stot = N + M;
    int mBlocks = (Stot + MOUT - 1) / MOUT;
    k_merge<<<dim3(mBlocks, KDIR), MBLK, 0, stream>>>(pX, pY, dX, dY, N, M, 0, tbl, accum);
  } else {
    // diagonal keys sorted separately (k=100 synthetic direction)
    if (N == M) {
      k_build<<<dim3(Tn, 1), 256, 0, stream>>>(X, N, 100, tbl, sPong, counts8, Tn, 0);
      k_build<<<dim3(Tn, 1), 256, 0, stream>>>(Y, N, 100, tbl, sPong + N, counts8, Tn, 1);
      sortJob(sPing, sPong, 2, N);
    } else {
      k_build<<<dim3(Tn, 1), 256, 0, stream>>>(X, N, 100, tbl, sPong, counts8, Tn, 0);
      sortJob(sPing, sPong, 1, N);
      k_build<<<dim3(Tm, 1), 256, 0, stream>>>(Y, M, 100, tbl, sPong + N, counts8, Tm, 0);
      sortJob(sPing + N, sPong + N, 1, M);
    }
    for (int k0 = 0; k0 < KDIR; k0 += Kc) {
      int kc = (KDIR - k0 < Kc) ? (KDIR - k0) : Kc;
      unsigned* pXin = cPong;
      unsigned* pYin = cPong + (size_t)kc * N;
      unsigned* pX = cPing;
      unsigned* pY = cPing + (size_t)kc * N;
      if (N == M) {
        k_build<<<dim3(Tn, kc), 256, 0, stream>>>(X, N, k0, tbl, pXin, counts8, Tn, 0);
        k_build<<<dim3(Tn, kc), 256, 0, stream>>>(Y, N, k0, tbl, pYin, counts8, Tn, kc);
        sortJob(cPing, cPong, 2 * kc, N);
      } else {
        k_build<<<dim3(Tn, kc), 256, 0, stream>>>(X, N, k0, tbl, pXin, counts8, Tn, 0);
        sortJob(pX, pXin, kc, N);
        k_build<<<dim3(Tm, kc), 256, 0, stream>>>(Y, M, k0, tbl, pYin, counts8, Tm, 0);
        sortJob(pY, pYin, kc, M);
      }
      int Stot = N + M;
      int mBlocks = (Stot + MOUT - 1) / MOUT;
      k_merge<<<dim3(mBlocks, kc), MBLK, 0, stream>>>(pX, pY, sPing, sPing + N, N, M, k0, tbl, accum);
    }
  }
  k_final<<<1, 1, 0, stream>>>(accum, (float*)d_out);
}

// Round 8
// 1026.620 us; speedup vs baseline: 3.2867x; 1.1243x over previous
//
#include <hip/hip_runtime.h>

#define KDIR 100
#define TILE 4096
#define NPASS 3
#define MBLK 256
#define MOUT 4096
#define MPT2 (MOUT / MBLK)

__device__ __forceinline__ unsigned encodeF(float f) {
  unsigned u = __float_as_uint(f);
  return u ^ ((u >> 31) ? 0xFFFFFFFFu : 0x80000000u);
}
__device__ __forceinline__ float decodeU(unsigned u) {
  return __uint_as_float(u ^ ((u >> 31) ? 0x80000000u : 0xFFFFFFFFu));
}

// tbl layout: [0..99]=cos, [128..227]=sin, [256..355]=c=(cos+sin)*invn, [384..483]=invn
// synthetic entry k=100: (0.5, 0.5, invn=1) -> diagonal key 0.5*(x+y)
__global__ void k_table(float* tbl, double* accum) {
  int k = threadIdx.x;
  const double PI = 3.14159265358979323846;
  if (k < KDIR) {
    double th = -PI * 0.5 + (double)k * (PI / (double)KDIR);
    float c = (float)cos(th), s = (float)sin(th);
    float invn = 1.0f / (c * c + s * s);
    tbl[k] = c; tbl[128 + k] = s; tbl[256 + k] = (c + s) * invn; tbl[384 + k] = invn;
  }
  if (k == 100) { tbl[100] = 0.5f; tbl[228] = 0.5f; tbl[484] = 1.0f; }
  if (k == 0) *accum = 0.0;
}

// Fused projection-build + pass-0 (shift=8) per-tile histogram.
// counts[((seg0+dir)*256 + d)*T + tile]
__global__ __launch_bounds__(256) void k_build(const float* __restrict__ P, int n, int kIdx,
                                               const float* __restrict__ tbl,
                                               unsigned* __restrict__ dst,
                                               unsigned* __restrict__ counts, int T, int seg0) {
  __shared__ unsigned h[256];
  int tid = threadIdx.x;
  h[tid] = 0;
  __syncthreads();
  int dir = blockIdx.y;
  int k = kIdx + dir;
  float ck = tbl[k], sk = tbl[128 + k], inv = tbl[384 + k];
  int tile = blockIdx.x;
  int start = tile * TILE;
  int nItems = min(TILE, n - start);
  unsigned* d0 = dst + (size_t)dir * n + start;
  const float* p0 = P + 2 * (size_t)start;
  if (nItems == TILE) {
    const float4* p4 = (const float4*)p0;
    uint2* o2 = (uint2*)d0;
#pragma unroll
    for (int i = 0; i < 8; ++i) {
      float4 v = p4[i * 256 + tid];
      unsigned ua = encodeF((v.x * ck + v.y * sk) * inv);
      unsigned ub = encodeF((v.z * ck + v.w * sk) * inv);
      o2[i * 256 + tid] = make_uint2(ua, ub);
      atomicAdd(&h[(ua >> 8) & 255u], 1u);
      atomicAdd(&h[(ub >> 8) & 255u], 1u);
    }
  } else {
    for (int j = tid; j < nItems; j += 256) {
      float x = p0[2 * j], y = p0[2 * j + 1];
      unsigned u = encodeF((x * ck + y * sk) * inv);
      d0[j] = u;
      atomicAdd(&h[(u >> 8) & 255u], 1u);
    }
  }
  __syncthreads();
  counts[((size_t)(seg0 + dir) * 256 + tid) * T + tile] = h[tid];
}

// Per-pass 8-bit histogram (passes 1,2); per-wave sub-histograms cut
// same-address LDS-atomic serialization.
__global__ __launch_bounds__(256) void k_hist8(const unsigned* __restrict__ keys,
                                               int L, int T, int shift,
                                               unsigned* __restrict__ counts) {
  __shared__ unsigned h[4][256];
  int tid = threadIdx.x;
  int w = tid >> 6;
  for (int i = tid; i < 4 * 256; i += 256) ((unsigned*)h)[i] = 0;
  __syncthreads();
  int seg = blockIdx.y, tile = blockIdx.x;
  const unsigned* base = keys + (size_t)seg * L + (size_t)tile * TILE;
  int nItems = min(TILE, L - tile * TILE);
  if (nItems == TILE) {
    const uint4* b4 = (const uint4*)base;
#pragma unroll
    for (int i = 0; i < 4; ++i) {
      uint4 v = b4[i * 256 + tid];
      atomicAdd(&h[w][(v.x >> shift) & 255u], 1u);
      atomicAdd(&h[w][(v.y >> shift) & 255u], 1u);
      atomicAdd(&h[w][(v.z >> shift) & 255u], 1u);
      atomicAdd(&h[w][(v.w >> shift) & 255u], 1u);
    }
  } else {
    for (int i = tid; i < nItems; i += 256)
      atomicAdd(&h[w][(base[i] >> shift) & 255u], 1u);
  }
  __syncthreads();
  counts[((size_t)seg * 256 + tid) * T + tile] =
      h[0][tid] + h[1][tid] + h[2][tid] + h[3][tid];
}

// Per-segment exclusive scan of [256*T] (digit-major): 256 threads, T elems each.
__global__ __launch_bounds__(256) void k_scanSeg(unsigned* __restrict__ counts, int T) {
  __shared__ unsigned tot[256];
  unsigned* c = counts + (size_t)blockIdx.x * 256 * T;
  int tid = threadIdx.x;
  int base = tid * T;
  unsigned sum = 0;
  for (int i = 0; i < T; ++i) sum += c[base + i];
  tot[tid] = sum;
  __syncthreads();
  for (int ofs = 1; ofs < 256; ofs <<= 1) {
    unsigned t = (tid >= ofs) ? tot[tid - ofs] : 0u;
    __syncthreads();
    tot[tid] += t;
    __syncthreads();
  }
  unsigned run = tot[tid] - sum;  // exclusive prefix of this thread's chunk
  for (int i = 0; i < T; ++i) {
    unsigned v = c[base + i];
    c[base + i] = run;
    run += v;
  }
}

// 8-bit scatter, STABLE, two-phase (rank -> LDS stage -> coalesced write).
// Ranking: 4 independent per-wave chains (round-7 scheme). Then keys are
// staged in LDS at tile-local sorted position (runG region reused), read
// back linearly, and written to global coalesced: addr = diffD[d] + pos.
__global__ __launch_bounds__(256) void k_scatter8(const unsigned* __restrict__ src,
                                                  unsigned* __restrict__ dst,
                                                  int L, int T, int shift,
                                                  const unsigned* __restrict__ counts) {
  __shared__ unsigned runG[4][4][256];  // [wave][group][digit]; reused as key stage
  __shared__ unsigned diffD[256];       // globalBase[d] - localStart[d]
  __shared__ unsigned wsum[4];
  int tid = threadIdx.x;
  int lane = tid & 63, w = tid >> 6;
  int seg = blockIdx.y, tile = blockIdx.x;
  const unsigned* sbase = src + (size_t)seg * L + (size_t)tile * TILE;
  int nItems = min(TILE, L - tile * TILE);
  for (int i = tid; i < 4 * 4 * 256; i += 256) ((unsigned*)runG)[i] = 0;
  __syncthreads();
  unsigned kk[16];
  unsigned rr[16];
  unsigned long long laneLT = (1ull << lane) - 1ull;
  int jbase = w * (TILE / 4);
#pragma unroll
  for (int i = 0; i < 16; ++i) {
    int j = jbase + i * 64 + lane;
    kk[i] = (j < nItems) ? sbase[j] : 0xFFFFFFFFu;
  }
#pragma unroll
  for (int s = 0; s < 4; ++s) {
    unsigned long long mask[4];
    unsigned prev[4];
#pragma unroll
    for (int g = 0; g < 4; ++g) {
      int i = g * 4 + s;
      int j = jbase + i * 64 + lane;
      bool valid = j < nItems;
      unsigned long long act = __ballot(valid);
      unsigned d = (kk[i] >> shift) & 255u;
      unsigned long long m = act;
#pragma unroll
      for (int b = 0; b < 8; ++b) {
        unsigned long long bal = __ballot((d >> b) & 1);
        m &= ((d >> b) & 1) ? bal : ~bal;
      }
      mask[g] = m;
      prev[g] = runG[w][g][d];
    }
#pragma unroll
    for (int g = 0; g < 4; ++g) {
      int i = g * 4 + s;
      int j = jbase + i * 64 + lane;
      if (j < nItems) {
        unsigned d = (kk[i] >> shift) & 255u;
        unsigned r = (unsigned)__popcll(mask[g] & laneLT);
        rr[i] = prev[g] + r;
        if (r == 0) runG[w][g][d] = prev[g] + (unsigned)__popcll(mask[g]);
      }
    }
  }
  __syncthreads();
  // fold: tid == digit. tile total per digit, block scan -> localStart,
  // diffD, then fold runG to local positions (w-major, g-minor).
  {
    unsigned tot = 0;
#pragma unroll
    for (int w2 = 0; w2 < 4; ++w2)
#pragma unroll
      for (int g2 = 0; g2 < 4; ++g2) tot += runG[w2][g2][tid];
    // shfl inclusive wave scan + cross-wave fold
    unsigned x = tot;
#pragma unroll
    for (int ofs = 1; ofs < 64; ofs <<= 1) {
      unsigned t = __shfl_up(x, ofs, 64);
      if (lane >= ofs) x += t;
    }
    if (lane == 63) wsum[w] = x;
    __syncthreads();
    unsigned basew = 0;
#pragma unroll
    for (int w2 = 0; w2 < 4; ++w2) basew += (w2 < w) ? wsum[w2] : 0u;
    unsigned localStart = basew + x - tot;
    diffD[tid] = counts[((size_t)seg * 256 + tid) * T + tile] - localStart;
    unsigned run = localStart;
#pragma unroll
    for (int w2 = 0; w2 < 4; ++w2)
#pragma unroll
      for (int g2 = 0; g2 < 4; ++g2) {
        unsigned t = runG[w2][g2][tid];
        runG[w2][g2][tid] = run;
        run += t;
      }
  }
  __syncthreads();
  // capture local positions to registers, then reuse runG as key stage
  unsigned lp[16];
#pragma unroll
  for (int i = 0; i < 16; ++i) {
    unsigned d = (kk[i] >> shift) & 255u;
    lp[i] = runG[w][i >> 2][d] + rr[i];
  }
  __syncthreads();
  unsigned* kbuf = &runG[0][0][0];  // 4096 u32
#pragma unroll
  for (int i = 0; i < 16; ++i) {
    int j = jbase + i * 64 + lane;
    if (j < nItems) kbuf[lp[i]] = kk[i];
  }
  __syncthreads();
  unsigned* dbase = dst + (size_t)seg * L;
#pragma unroll
  for (int i = 0; i < 16; ++i) {
    int pos = i * 256 + tid;
    if (pos < nItems) {
      unsigned k = kbuf[pos];
      unsigned d = (k >> shift) & 255u;
      dbase[diffD[d] + (unsigned)pos] = k;
    }
  }
}

__device__ __forceinline__ float scaledAt(const unsigned* __restrict__ s, int len, int j,
                                          float c, int rev) {
  return c * decodeU(s[rev ? (len - 1 - j) : j]);
}

__device__ int mergeSplit(const unsigned* __restrict__ U, int n,
                          const unsigned* __restrict__ sV, int m,
                          float c, int rev, int o) {
  int lo = o - m; if (lo < 0) lo = 0;
  int hi = o < n ? o : n;
  while (lo < hi) {
    int mid = (lo + hi + 1) >> 1;
    if (decodeU(U[mid - 1]) <= scaledAt(sV, m, o - mid, c, rev)) lo = mid;
    else hi = mid - 1;
  }
  return lo;
}

__device__ __forceinline__ int ldsSplit(const float* __restrict__ a, int n,
                                        const float* __restrict__ b, int m, int o) {
  int lo = o - m; if (lo < 0) lo = 0;
  int hi = o < n ? o : n;
  while (lo < hi) {
    int mid = (lo + hi + 1) >> 1;
    if (a[mid - 1] <= b[o - mid]) lo = mid;
    else hi = mid - 1;
  }
  return lo;
}

__global__ __launch_bounds__(MBLK) void k_merge(const unsigned* __restrict__ pX,
                                                const unsigned* __restrict__ pY,
                                                const unsigned* __restrict__ sx,
                                                const unsigned* __restrict__ sy,
                                                int N, int M, int k0,
                                                const float* __restrict__ tbl,
                                                double* __restrict__ accum) {
  const float FMAX = 3.402823466e38f;
  __shared__ float sA[MOUT];
  __shared__ float sB[MOUT];
  __shared__ int splits[4];
  __shared__ float red[MBLK];
  int kl = blockIdx.y;
  float c = tbl[256 + k0 + kl];
  int rev = c < 0.0f ? 1 : 0;
  int Stot = N + M;
  int o0 = blockIdx.x * MOUT;
  int outCnt = min(MOUT, Stot - o0);
  const unsigned* U1 = pX + (size_t)kl * N;
  const unsigned* U2 = pY + (size_t)kl * M;
  int tid = threadIdx.x;
  if (tid == 0)        splits[0] = mergeSplit(U1, N, sy, M, c, rev, o0);
  else if (tid == 64)  splits[1] = mergeSplit(U1, N, sy, M, c, rev, o0 + outCnt);
  else if (tid == 128) splits[2] = mergeSplit(U2, M, sx, N, c, rev, o0);
  else if (tid == 192) splits[3] = mergeSplit(U2, M, sx, N, c, rev, o0 + outCnt);
  __syncthreads();
  int aLo = splits[0], aCnt = splits[1] - aLo;
  int bLo = o0 - aLo, bCnt = outCnt - aCnt;
  int a2Lo = splits[2], a2Cnt = splits[3] - a2Lo;
  int b2Lo = o0 - a2Lo, b2Cnt = outCnt - a2Cnt;
  for (int i = tid; i < aCnt; i += MBLK) sA[i] = decodeU(U1[aLo + i]);
  for (int i = tid; i < bCnt; i += MBLK) {
    int j = bLo + i;
    sA[aCnt + i] = c * decodeU(sy[rev ? (M - 1 - j) : j]);
  }
  for (int i = tid; i < a2Cnt; i += MBLK) sB[i] = decodeU(U2[a2Lo + i]);
  for (int i = tid; i < b2Cnt; i += MBLK) {
    int j = b2Lo + i;
    sB[a2Cnt + i] = c * decodeU(sx[rev ? (N - 1 - j) : j]);
  }
  __syncthreads();
  float acc = 0.0f;
  int lo0 = tid * MPT2;
  if (lo0 < outCnt) {
    int cnt = min(MPT2, outCnt - lo0);
    int la = ldsSplit(sA, aCnt, sA + aCnt, bCnt, lo0);
    int lb = lo0 - la;
    int la2 = ldsSplit(sB, a2Cnt, sB + a2Cnt, b2Cnt, lo0);
    int lb2 = lo0 - la2;
    float u1 = la < aCnt ? sA[la] : FMAX;
    float v1 = lb < bCnt ? sA[aCnt + lb] : FMAX;
    float u2 = la2 < a2Cnt ? sB[la2] : FMAX;
    float v2 = lb2 < b2Cnt ? sB[a2Cnt + lb2] : FMAX;
    for (int s = 0; s < cnt; ++s) {
      float Av, Bv;
      if (u1 <= v1) { Av = u1; ++la; u1 = la < aCnt ? sA[la] : FMAX; }
      else          { Av = v1; ++lb; v1 = lb < bCnt ? sA[aCnt + lb] : FMAX; }
      if (u2 <= v2) { Bv = u2; ++la2; u2 = la2 < a2Cnt ? sB[la2] : FMAX; }
      else          { Bv = v2; ++lb2; v2 = lb2 < b2Cnt ? sB[a2Cnt + lb2] : FMAX; }
      acc += fabsf(Av - Bv);
    }
  }
  red[tid] = acc;
  __syncthreads();
  for (int ofs = MBLK / 2; ofs > 0; ofs >>= 1) {
    if (tid < ofs) red[tid] += red[tid + ofs];
    __syncthreads();
  }
  if (tid == 0) atomicAdd(accum, (double)red[0]);
}

__global__ void k_final(const double* __restrict__ accum, float* __restrict__ out) {
  out[0] = (float)(*accum / (double)KDIR);
}

extern "C" void kernel_launch(void* const* d_in, const int* in_sizes, int n_in,
                              void* d_out, int out_size, void* d_ws, size_t ws_size,
                              hipStream_t stream) {
  const float* X = (const float*)d_in[0];
  const float* Y = (const float*)d_in[1];
  int N = in_sizes[0] / 2;
  int M = in_sizes[1] / 2;

  char* ws = (char*)d_ws;
  size_t off = 0;
  auto alloc = [&](size_t b) -> void* {
    void* p = ws + off;
    off += (b + 255) & ~(size_t)255;
    return p;
  };
  float* tbl = (float*)alloc(512 * sizeof(float));
  double* accum = (double*)alloc(256);
  unsigned* sPing = (unsigned*)alloc((size_t)(N + M) * 4);
  unsigned* sPong = (unsigned*)alloc((size_t)(N + M) * 4);

  int Tn = (N + TILE - 1) / TILE;
  int Tm = (M + TILE - 1) / TILE;
  int Tmax = Tn > Tm ? Tn : Tm;
  int mx = N > M ? N : M;

  // per direction: ping+pong keys (2 segs) + counts (2 segs x 256 x Tmax);
  // reserve 2 extra segment rows (fused diagonal sort).
  size_t perDir = (size_t)(N + M) * 8 + (size_t)2 * 256 * Tmax * 4;
  size_t reserve = (size_t)2 * mx * 8 + (size_t)2 * 256 * Tmax * 4;
  size_t remain = ws_size > off ? ws_size - off : 0;
  remain = remain > reserve ? remain - reserve : 0;
  int Kc = (int)(remain / perDir);
  if (Kc > KDIR) Kc = KDIR;
  if (Kc < 1) Kc = 1;
  int maxSegs = 2 * Kc + 2;
  unsigned* counts8 = (unsigned*)alloc((size_t)maxSegs * 256 * Tmax * 4);
  unsigned* cPing = (unsigned*)alloc(((size_t)Kc * (N + M) + 2 * (size_t)mx) * 4);
  unsigned* cPong = (unsigned*)alloc(((size_t)Kc * (N + M) + 2 * (size_t)mx) * 4);

  k_table<<<1, 128, 0, stream>>>(tbl, accum);

  // pass-0 counts are prefilled by k_build; passes 1,2 run k_hist8.
  // input staged in `pong`; after 3 (odd) passes sorted result lands in `ping`.
  auto sortJob = [&](unsigned* ping, unsigned* pong, int segs, int L) {
    int T = (L + TILE - 1) / TILE;
    unsigned* s = pong;
    unsigned* d = ping;
    for (int p = 0; p < NPASS; ++p) {
      int shift = 8 * (p + 1);
      if (p > 0)
        k_hist8<<<dim3(T, segs), 256, 0, stream>>>(s, L, T, shift, counts8);
      k_scanSeg<<<segs, 256, 0, stream>>>(counts8, T);
      k_scatter8<<<dim3(T, segs), 256, 0, stream>>>(s, d, L, T, shift, counts8);
      unsigned* t = s; s = d; d = t;
    }
  };

  bool fused = (N == M) && (Kc == KDIR);

  if (fused) {
    // single 202-segment sort: [0..99]=projX dirs, [100..199]=projY dirs,
    // [200]=diagX, [201]=diagY. All segments length N.
    unsigned* dXin = cPong + (size_t)2 * KDIR * N;
    unsigned* dYin = dXin + N;
    k_build<<<dim3(Tn, KDIR), 256, 0, stream>>>(X, N, 0, tbl, cPong, counts8, Tn, 0);
    k_build<<<dim3(Tn, KDIR), 256, 0, stream>>>(Y, N, 0, tbl, cPong + (size_t)KDIR * N,
                                                counts8, Tn, KDIR);
    k_build<<<dim3(Tn, 1), 256, 0, stream>>>(X, N, 100, tbl, dXin, counts8, Tn, 2 * KDIR);
    k_build<<<dim3(Tn, 1), 256, 0, stream>>>(Y, N, 100, tbl, dYin, counts8, Tn, 2 * KDIR + 1);
    sortJob(cPing, cPong, 2 * KDIR + 2, N);
    unsigned* pX = cPing;
    unsigned* pY = cPing + (size_t)KDIR * N;
    unsigned* dX = cPing + (size_t)2 * KDIR * N;
    unsigned* dY = dX + N;
    int Stot = N + M;
    int mBlocks = (Stot + MOUT - 1) / MOUT;
    k_merge<<<dim3(mBlocks, KDIR), MBLK, 0, stream>>>(pX, pY, dX, dY, N, M, 0, tbl, accum);
  } else {
    // diagonal keys sorted separately (k=100 synthetic direction)
    if (N == M) {
      k_build<<<dim3(Tn, 1), 256, 0, stream>>>(X, N, 100, tbl, sPong, counts8, Tn, 0);
      k_build<<<dim3(Tn, 1), 256, 0, stream>>>(Y, N, 100, tbl, sPong + N, counts8, Tn, 1);
      sortJob(sPing, sPong, 2, N);
    } else {
      k_build<<<dim3(Tn, 1), 256, 0, stream>>>(X, N, 100, tbl, sPong, counts8, Tn, 0);
      sortJob(sPing, sPong, 1, N);
      k_build<<<dim3(Tm, 1), 256, 0, stream>>>(Y, M, 100, tbl, sPong + N, counts8, Tm, 0);
      sortJob(sPing + N, sPong + N, 1, M);
    }
    for (int k0 = 0; k0 < KDIR; k0 += Kc) {
      int kc = (KDIR - k0 < Kc) ? (KDIR - k0) : Kc;
      unsigned* pXin = cPong;
      unsigned* pYin = cPong + (size_t)kc * N;
      unsigned* pX = cPing;
      unsigned* pY = cPing + (size_t)kc * N;
      if (N == M) {
        k_build<<<dim3(Tn, kc), 256, 0, stream>>>(X, N, k0, tbl, pXin, counts8, Tn, 0);
        k_build<<<dim3(Tn, kc), 256, 0, stream>>>(Y, N, k0, tbl, pYin, counts8, Tn, kc);
        sortJob(cPing, cPong, 2 * kc, N);
      } else {
        k_build<<<dim3(Tn, kc), 256, 0, stream>>>(X, N, k0, tbl, pXin, counts8, Tn, 0);
        sortJob(pX, pXin, kc, N);
        k_build<<<dim3(Tm, kc), 256, 0, stream>>>(Y, M, k0, tbl, pYin, counts8, Tm, 0);
        sortJob(pY, pYin, kc, M);
      }
      int Stot = N + M;
      int mBlocks = (Stot + MOUT - 1) / MOUT;
      k_merge<<<dim3(mBlocks, kc), MBLK, 0, stream>>>(pX, pY, sPing, sPing + N, N, M, k0, tbl, accum);
    }
  }
  k_final<<<1, 1, 0, stream>>>(accum, (float*)d_out);
}